// Round 11
// baseline (542.216 us; speedup 1.0000x reference)
//
#include <hip/hip_runtime.h>
#include <math.h>
#include <float.h>

// Problem constants (HierNet_55705725829422)
#define NN 50000      // nodes
#define EE 800000     // edges
#define CAP 64        // max edges processed per node in aggregate (Poisson(16): P(>64) ~ 1e-19)
#define NB 196        // scan blocks = ceil(NN/256)

typedef unsigned short ushort_t;
typedef short short8 __attribute__((ext_vector_type(8)));
typedef float floatx4 __attribute__((ext_vector_type(4)));

__device__ __constant__ float kAVG_LOG = 2.8332133440562162f; // log(17)

__device__ inline ushort_t f2bf(float v) {
    union { float f; unsigned u; } x; x.f = v;
    unsigned r = x.u + 0x7fffu + ((x.u >> 16) & 1u);
    return (ushort_t)(r >> 16);
}
__device__ inline float bf2f(ushort_t b) {
    union { unsigned u; float f; } x; x.u = ((unsigned)b) << 16; return x.f;
}
__device__ inline float bitsf(unsigned u) {
    union { unsigned u; float f; } x; x.u = u; return x.f;
}
__device__ inline void splitbf(float v, ushort_t& hi, ushort_t& lo) {
    hi = f2bf(v);
    lo = f2bf(v - bf2f(hi));
}

// merged init: zero cnt/cnt2/pool, cast x -> bf16
__global__ __launch_bounds__(256) void init_kernel(int* cnt, int* cnt2, float* pool,
                                                   const float* __restrict__ x, ushort_t* __restrict__ xb) {
    int i = blockIdx.x * 256 + threadIdx.x;
    if (i < NN * 32) xb[i] = f2bf(x[i]);
    if (i < NN) { cnt[i] = 0; cnt2[i] = 0; }
    if (i < 64 * 64) pool[i] = 0.f;
}

// in-degree histogram
__global__ __launch_bounds__(256) void hist_kernel(const int* __restrict__ ei, int* __restrict__ cnt) {
    int e = blockIdx.x * 256 + threadIdx.x;
    if (e < EE) atomicAdd(&cnt[ei[EE + e]], 1);
}

// exclusive scan of cnt -> off, three small kernels
__global__ __launch_bounds__(256) void scan_part(const int* __restrict__ cnt, int* __restrict__ sums) {
    __shared__ int red[256];
    int tid = threadIdx.x;
    int i = blockIdx.x * 256 + tid;
    red[tid] = (i < NN) ? cnt[i] : 0;
    __syncthreads();
    for (int s = 128; s > 0; s >>= 1) {
        if (tid < s) red[tid] += red[tid + s];
        __syncthreads();
    }
    if (tid == 0) sums[blockIdx.x] = red[0];
}
__global__ __launch_bounds__(256) void scan_top(int* __restrict__ sums) {
    __shared__ int buf[256];
    int tid = threadIdx.x;
    int v = (tid < NB) ? sums[tid] : 0;
    buf[tid] = v;
    __syncthreads();
    for (int ofs = 1; ofs < 256; ofs <<= 1) {
        int t = (tid >= ofs) ? buf[tid - ofs] : 0;
        __syncthreads();
        buf[tid] += t;
        __syncthreads();
    }
    if (tid < NB) sums[tid] = buf[tid] - v;  // exclusive
}
__global__ __launch_bounds__(256) void scan_final(const int* __restrict__ cnt, const int* __restrict__ sums,
                                                  int* __restrict__ off) {
    __shared__ int buf[256];
    int tid = threadIdx.x;
    int i = blockIdx.x * 256 + tid;
    int v = (i < NN) ? cnt[i] : 0;
    buf[tid] = v;
    __syncthreads();
    for (int ofs = 1; ofs < 256; ofs <<= 1) {
        int t = (tid >= ofs) ? buf[tid - ofs] : 0;
        __syncthreads();
        buf[tid] += t;
        __syncthreads();
    }
    if (i < NN) off[i] = sums[blockIdx.x] + buf[tid] - v;
}

// fill compact CSR (12.8 MB, L2-resident -> line combining). 1 edge/thread for occupancy.
__global__ __launch_bounds__(256) void fill_csr(const int* __restrict__ ei, const float* __restrict__ ea,
                                                const int* __restrict__ off, int* __restrict__ cnt2,
                                                float4* __restrict__ csr) {
    int e = blockIdx.x * 256 + threadIdx.x;
    if (e >= EE) return;
    int s = ei[e];
    int d = ei[EE + e];
    float2 v = *(const float2*)(ea + 2 * e);
    int p = atomicAdd(&cnt2[d], 1);
    csr[off[d] + p] = make_float4(bitsf((unsigned)s), v.x, v.y, 0.f);
}

// per-layer A/B-projection weight prep: U, Wab (fp32), bias_ab
template <int F>
__global__ __launch_bounds__(256) void prep_ab(const float* __restrict__ We, const float* __restrict__ be,
                                               const float* __restrict__ Wpre, const float* __restrict__ bpre,
                                               float* __restrict__ U, float* __restrict__ Wab,
                                               float* __restrict__ bias_ab) {
    const int TF = 2 * F;
    int tid = threadIdx.x;
    for (int idx = tid; idx < 2 * TF; idx += 256) {
        int c = idx / TF, f = idx % TF;
        int t = f / F, o = f % F;
        float s = 0.f;
        for (int g = 0; g < F; ++g)
            s += We[c * F + g] * Wpre[((size_t)t * 3 * F + 2 * F + g) * F + o];
        U[idx] = s;
    }
    for (int idx = tid; idx < F * 2 * TF; idx += 256) {
        int g = idx / (2 * TF), cc = idx % (2 * TF);
        int t, o, row;
        if (cc < TF) { t = cc / F; o = cc % F; row = g; }
        else { int c2 = cc - TF; t = c2 / F; o = c2 % F; row = F + g; }
        Wab[idx] = Wpre[((size_t)t * 3 * F + row) * F + o];
    }
    for (int cc = tid; cc < 2 * TF; cc += 256) {
        float v = 0.f;
        if (cc < TF) {
            int t = cc / F, o = cc % F;
            float s = 0.f;
            for (int g = 0; g < F; ++g)
                s += be[g] * Wpre[((size_t)t * 3 * F + 2 * F + g) * F + o];
            v = s + bpre[t * F + o];
        }
        bias_ab[cc] = v;
    }
}

// Folded Z/final weights, split to bf16 hi/lo, stored COL-MAJOR [192 cols][KT]
template <int F>
__global__ __launch_bounds__(256) void prep_zf(const float* __restrict__ Wpost, const float* __restrict__ Wlin,
                                               const float* __restrict__ bpost, const float* __restrict__ blin,
                                               ushort_t* __restrict__ Bh, ushort_t* __restrict__ Bl,
                                               float* __restrict__ bias_zf) {
    const int KT = 9 * F;
    int bx = blockIdx.x;  // 12 blocks x 16 cols
    int tid = threadIdx.x;
    for (int idx = tid; idx < 16 * KT; idx += 256) {
        int jj = idx / KT, k = idx % KT;
        int jg = bx * 16 + jj;
        int b = jg >> 6, j = jg & 63;
        float v = 0.f;
        if (k < F) {
            if (b == 0) {
                float s = 0.f;
                for (int t = 0; t < 2; ++t)
                    for (int c = 0; c < 32; ++c)
                        s += Wpost[((size_t)t * 13 * F + k) * 32 + c] * Wlin[(t * 32 + c) * 64 + j];
                v = s;
            }
        } else {
            int r = k - F;
            int t = r / (4 * F), rr = r - t * 4 * F;
            float s = 0.f;
            for (int c = 0; c < 32; ++c)
                s += Wpost[((size_t)t * 13 * F + F + b * 4 * F + rr) * 32 + c] * Wlin[(t * 32 + c) * 64 + j];
            v = s;
        }
        ushort_t h_, l_;
        splitbf(v, h_, l_);
        Bh[(size_t)jg * KT + k] = h_;
        Bl[(size_t)jg * KT + k] = l_;
    }
    if (bx == 0) {
        for (int j = tid; j < 64; j += 256) {
            float s = blin[j];
            for (int t = 0; t < 2; ++t)
                for (int c = 0; c < 32; ++c)
                    s += bpost[t * 32 + c] * Wlin[(t * 32 + c) * 64 + j];
            bias_zf[j] = s;
        }
    }
}

// fp32 GEMM: [Ca | Cb] = A[MxK]@B[KxN] + bias. Columns < bstart -> fp32 Ca; >= bstart -> bf16 Cb.
__global__ __launch_bounds__(256) void gemm_bias(const float* __restrict__ A, const float* __restrict__ B,
                                                 const float* __restrict__ bias, float* __restrict__ Ca,
                                                 ushort_t* __restrict__ Cb, int M, int K, int Ncols, int bstart) {
    __shared__ float As[32][132];
    __shared__ float Bs[32][68];
    int m0 = blockIdx.x * 128, c0 = blockIdx.y * 64;
    int tid = threadIdx.x;
    int tx = tid & 15, ty = tid >> 4;
    int ms = tid >> 3, u = tid & 7;
    float acc[8][4] = {};
    for (int k0 = 0; k0 < K; k0 += 32) {
#pragma unroll
        for (int p = 0; p < 4; ++p) {
            int m = ms + 32 * p;
            int gm = m0 + m;
            float4 v = make_float4(0.f, 0.f, 0.f, 0.f);
            if (gm < M) v = *(const float4*)(A + (size_t)gm * K + k0 + u * 4);
            As[u * 4 + 0][m] = v.x; As[u * 4 + 1][m] = v.y;
            As[u * 4 + 2][m] = v.z; As[u * 4 + 3][m] = v.w;
        }
#pragma unroll
        for (int p = 0; p < 2; ++p) {
            int idx = tid + 256 * p;
            int kk = idx >> 4, q = idx & 15;
            *(float4*)&Bs[kk][q * 4] = *(const float4*)(B + (size_t)(k0 + kk) * Ncols + c0 + q * 4);
        }
        __syncthreads();
#pragma unroll 8
        for (int k = 0; k < 32; ++k) {
            float a0[8], b0[4];
            *(float4*)&a0[0] = *(const float4*)&As[k][ty * 8];
            *(float4*)&a0[4] = *(const float4*)&As[k][ty * 8 + 4];
            *(float4*)&b0[0] = *(const float4*)&Bs[k][tx * 4];
#pragma unroll
            for (int i = 0; i < 8; ++i)
#pragma unroll
                for (int j = 0; j < 4; ++j) acc[i][j] = fmaf(a0[i], b0[j], acc[i][j]);
        }
        __syncthreads();
    }
    float bj[4];
#pragma unroll
    for (int j = 0; j < 4; ++j) bj[j] = bias[c0 + tx * 4 + j];
    bool bside = (c0 >= bstart);
    int TFw = bstart;  // row stride of both halves
#pragma unroll
    for (int i = 0; i < 8; ++i) {
        int gm = m0 + ty * 8 + i;
        if (gm >= M) continue;
        float v0 = acc[i][0] + bj[0], v1 = acc[i][1] + bj[1];
        float v2 = acc[i][2] + bj[2], v3 = acc[i][3] + bj[3];
        if (!bside) {
            *(float4*)(Ca + (size_t)gm * TFw + c0 + tx * 4) = make_float4(v0, v1, v2, v3);
        } else {
            ushort4 w;
            w.x = f2bf(v0); w.y = f2bf(v1); w.z = f2bf(v2); w.w = f2bf(v3);
            *(ushort4*)(Cb + (size_t)gm * TFw + (c0 - bstart) + tx * 4) = w;
        }
    }
}

// aggregate: ONE wave per node, compact CSR (off[n] base), bf16 gather. Emits agg as plain bf16.
template <int F>
__global__ __launch_bounds__(256) void aggregate(const float* __restrict__ ABa, const ushort_t* __restrict__ ABb,
                                                 const int* __restrict__ cnt, const int* __restrict__ off,
                                                 const float4* __restrict__ csr, const float* __restrict__ U,
                                                 ushort_t* __restrict__ agg_b, float2* __restrict__ sc) {
    const int TF = 2 * F;
    const int FPL = TF / 64;  // 1 (F=32) or 2 (F=64)
    int lane = threadIdx.x & 63;
    int n = blockIdx.x * 4 + (threadIdx.x >> 6);
    if (n >= NN) return;
    int f0 = FPL * lane;

    float base[FPL], u0[FPL], u1[FPL], sum[FPL], sq[FPL], mn[FPL], mx[FPL];
#pragma unroll
    for (int r = 0; r < FPL; ++r) {
        base[r] = ABa[(size_t)n * TF + f0 + r];
        u0[r] = U[f0 + r];
        u1[r] = U[TF + f0 + r];
        sum[r] = 0.f; sq[r] = 0.f; mn[r] = FLT_MAX; mx[r] = -FLT_MAX;
    }
    int deg = cnt[n];
    int ec = deg < CAP ? deg : CAP;
    if (ec > 0) {
        int ebase = off[n];
        int myi = lane < ec ? lane : ec - 1;
        float4 ent = csr[ebase + myi];
        int msrc = __float_as_int(ent.x);
        float meax = ent.y, meay = ent.z;
        for (int e = 0; e < ec; e += 8) {
            int sb[8]; float ex[8], ey[8];
            unsigned wv[8];
#pragma unroll
            for (int i = 0; i < 8; ++i) {
                sb[i] = __shfl(msrc, e + i);
                ex[i] = __shfl(meax, e + i);
                ey[i] = __shfl(meay, e + i);
            }
#pragma unroll
            for (int i = 0; i < 8; ++i) {
                if (e + i < ec) {
                    if constexpr (FPL == 2)
                        wv[i] = *(const unsigned*)(ABb + (size_t)sb[i] * TF + f0);
                    else
                        wv[i] = ABb[(size_t)sb[i] * TF + f0];
                }
            }
#pragma unroll
            for (int i = 0; i < 8; ++i) {
                if (e + i < ec) {
                    float v[FPL];
                    if constexpr (FPL == 2) {
                        v[0] = bitsf(wv[i] << 16);
                        v[1] = bitsf(wv[i] & 0xffff0000u);
                    } else {
                        v[0] = bitsf(wv[i] << 16);
                    }
#pragma unroll
                    for (int r = 0; r < FPL; ++r) {
                        float q = fmaf(ex[i], u0[r], fmaf(ey[i], u1[r], v[r]));
                        sum[r] += q;
                        sq[r] = fmaf(q, q, sq[r]);
                        mn[r] = fminf(mn[r], q);
                        mx[r] = fmaxf(mx[r], q);
                    }
                }
            }
        }
    }
    float d = (float)(deg > 1 ? deg : 1);
    float inv_d = 1.f / d;
    bool has = deg > 0;
#pragma unroll
    for (int r = 0; r < FPL; ++r) {
        float mean_q = sum[r] * inv_d;
        float var = sq[r] * inv_d - mean_q * mean_q;
        float stdv = sqrtf(fmaxf(var, 0.f) + 1e-5f);
        float mean = has ? base[r] + mean_q : 0.f;
        float vmn = has ? base[r] + mn[r] : 0.f;
        float vmx = has ? base[r] + mx[r] : 0.f;
        int f = f0 + r;
        int t = f / F, o = f - t * F;
        size_t rowb = (size_t)n * (4 * TF) + (size_t)t * (4 * F);
        agg_b[rowb + o] = f2bf(mean);
        agg_b[rowb + F + o] = f2bf(vmn);
        agg_b[rowb + 2 * F + o] = f2bf(vmx);
        agg_b[rowb + 3 * F + o] = f2bf(stdv);
    }
    if (lane == 0) {
        float logd = logf(d + 1.f);
        sc[n] = make_float2(logd / kAVG_LOG, kAVG_LOG / logd);
    }
}

// MFMA merged Z+final GEMM. A bf16 (single), B split hi/lo: Y = Ah@Bh + Ah@Bl.
// Block 64 rows x 192 cols; wave w owns col-frags {w, w+4, w+8} x 4 row-frags.
// Register-prefetch pipeline: k0+1 global loads issued before k0's MFMA block.
template <int F, bool POOL>
__global__ __launch_bounds__(256) void gemm_zf(
    const ushort_t* __restrict__ xs_b, const ushort_t* __restrict__ agg_b,
    const ushort_t* __restrict__ Bh, const ushort_t* __restrict__ Bl,
    const float* __restrict__ bias_zf, const float2* __restrict__ sc,
    float* __restrict__ H, ushort_t* __restrict__ H_b,
    const int* __restrict__ batch, float* __restrict__ pool) {
    const int KT = 9 * F;
    extern __shared__ char smem[];
    ushort_t* A_s  = (ushort_t*)smem;        // [64][40]
    ushort_t* Bh_s = A_s + 64 * 40;          // [192][40]
    ushort_t* Bl_s = Bh_s + 192 * 40;        // [192][40]
    float* hbuf = (float*)smem;              // POOL alias [64][68]

    int m0 = blockIdx.x * 64;
    int tid = threadIdx.x;
    int lane = tid & 63;
    int wave = tid >> 6;
    int ln = lane & 15, quad = lane >> 4;

    floatx4 acc[4][3];
#pragma unroll
    for (int i = 0; i < 4; ++i)
#pragma unroll
        for (int j = 0; j < 3; ++j) acc[i][j] = (floatx4)(0.f);

    int arow = tid >> 2, asg = tid & 3;
    int agm = m0 + arow;
    int bcol[3], bsg[3];
#pragma unroll
    for (int p = 0; p < 3; ++p) {
        int idx = tid + 256 * p;
        bcol[p] = idx >> 2;
        bsg[p] = idx & 3;
    }

    const short8 zero8 = {0, 0, 0, 0, 0, 0, 0, 0};
    short8 pa, pbh[3], pbl[3];
    // prefetch k0 = 0
    {
        int c0 = asg * 8;  // always < F at k0=0
        pa = zero8;
        if (agm < NN) pa = *(const short8*)(xs_b + (size_t)agm * F + c0);
#pragma unroll
        for (int p = 0; p < 3; ++p) {
            pbh[p] = *(const short8*)(Bh + (size_t)bcol[p] * KT + bsg[p] * 8);
            pbl[p] = *(const short8*)(Bl + (size_t)bcol[p] * KT + bsg[p] * 8);
        }
    }

    for (int k0 = 0; k0 < KT; k0 += 32) {
        // write staged regs -> LDS
        *(short8*)&A_s[arow * 40 + asg * 8] = pa;
#pragma unroll
        for (int p = 0; p < 3; ++p) {
            *(short8*)&Bh_s[bcol[p] * 40 + bsg[p] * 8] = pbh[p];
            *(short8*)&Bl_s[bcol[p] * 40 + bsg[p] * 8] = pbl[p];
        }
        __syncthreads();
        short8 ah[4], bh[3], bl[3];
#pragma unroll
        for (int rf = 0; rf < 4; ++rf)
            ah[rf] = *(short8*)&A_s[(rf * 16 + ln) * 40 + quad * 8];
#pragma unroll
        for (int b = 0; b < 3; ++b) {
            int col = b * 64 + wave * 16 + ln;
            bh[b] = *(short8*)&Bh_s[col * 40 + quad * 8];
            bl[b] = *(short8*)&Bl_s[col * 40 + quad * 8];
        }
        // issue next-k0 global loads (overlap with MFMA below)
        int kn = k0 + 32;
        if (kn < KT) {
            int c0 = kn + asg * 8;
            pa = zero8;
            if (agm < NN) {
                pa = (c0 < F) ? *(const short8*)(xs_b + (size_t)agm * F + c0)
                              : *(const short8*)(agg_b + (size_t)agm * 8 * F + (c0 - F));
            }
#pragma unroll
            for (int p = 0; p < 3; ++p) {
                pbh[p] = *(const short8*)(Bh + (size_t)bcol[p] * KT + kn + bsg[p] * 8);
                pbl[p] = *(const short8*)(Bl + (size_t)bcol[p] * KT + kn + bsg[p] * 8);
            }
        }
#pragma unroll
        for (int rf = 0; rf < 4; ++rf)
#pragma unroll
            for (int b = 0; b < 3; ++b) {
                acc[rf][b] = __builtin_amdgcn_mfma_f32_16x16x32_bf16(ah[rf], bh[b], acc[rf][b], 0, 0, 0);
                acc[rf][b] = __builtin_amdgcn_mfma_f32_16x16x32_bf16(ah[rf], bl[b], acc[rf][b], 0, 0, 0);
            }
        __syncthreads();
    }

    int ocol = wave * 16 + ln;  // output col 0..63
    float bcolv = bias_zf[ocol];

#pragma unroll
    for (int rf = 0; rf < 4; ++rf) {
#pragma unroll
        for (int reg = 0; reg < 4; ++reg) {
            int r = rf * 16 + quad * 4 + reg;
            int gm = m0 + r;
            float2 s = make_float2(0.f, 0.f);
            if (gm < NN) s = sc[gm];
            float y = acc[rf][0][reg] + s.x * acc[rf][1][reg] + s.y * acc[rf][2][reg] + bcolv;
            y = fmaxf(y, 0.f);
            if (POOL) {
                hbuf[r * 68 + ocol] = (gm < NN) ? y : 0.f;
            } else if (gm < NN) {
                H[(size_t)gm * 64 + ocol] = y;
                H_b[(size_t)gm * 64 + ocol] = f2bf(y);
            }
        }
    }
    if (POOL) {
        __syncthreads();
        int col = tid & 63, grp = tid >> 6;
        float a = 0.f;
        int cur = -1;
        for (int i = 0; i < 16; ++i) {
            int r = grp * 16 + i;
            int gm = m0 + r;
            if (gm >= NN) break;
            int b = batch[gm];
            if (b != cur) {
                if (cur >= 0) atomicAdd(&pool[cur * 64 + col], a);
                cur = b; a = 0.f;
            }
            a += hbuf[r * 68 + col];
        }
        if (cur >= 0) atomicAdd(&pool[cur * 64 + col], a);
    }
}

__global__ __launch_bounds__(256) void head_kernel(const float* __restrict__ gpool, const float* __restrict__ hls,
                                                   const float* __restrict__ W1, const float* __restrict__ b1,
                                                   const float* __restrict__ W2, const float* __restrict__ b2,
                                                   const float* __restrict__ W3, const float* __restrict__ b3,
                                                   float* __restrict__ out) {
    __shared__ float gin[64][96];
    __shared__ float r1[64][64];
    __shared__ float r2[64][64];
    int tid = threadIdx.x;
    for (int idx = tid; idx < 64 * 96; idx += 256) {
        int g = idx / 96, j = idx % 96;
        gin[g][j] = (j < 64) ? gpool[g * 64 + j] : hls[g * 32 + (j - 64)];
    }
    __syncthreads();
    for (int idx = tid; idx < 64 * 64; idx += 256) {
        int g = idx / 64, j = idx % 64;
        float acc = b1[j];
        for (int k = 0; k < 96; ++k) acc = fmaf(gin[g][k], W1[k * 64 + j], acc);
        r1[g][j] = fmaxf(acc, 0.f);
    }
    __syncthreads();
    for (int idx = tid; idx < 64 * 64; idx += 256) {
        int g = idx / 64, j = idx % 64;
        float acc = b2[j];
        for (int k = 0; k < 64; ++k) acc = fmaf(r1[g][k], W2[k * 64 + j], acc);
        r2[g][j] = fmaxf(acc, 0.f);
    }
    __syncthreads();
    if (tid < 64) {
        float acc = b3[0];
        for (int k = 0; k < 64; ++k) acc = fmaf(r2[tid][k], W3[k], acc);
        out[tid] = acc;
    }
}

extern "C" void kernel_launch(void* const* d_in, const int* in_sizes, int n_in,
                              void* d_out, int out_size, void* d_ws, size_t ws_size,
                              hipStream_t stream) {
    (void)in_sizes; (void)n_in; (void)out_size; (void)ws_size;
    const float* x     = (const float*)d_in[0];
    const float* eattr = (const float*)d_in[1];
    const float* hls   = (const float*)d_in[2];
    const int*   eidx  = (const int*)d_in[3];
    const int*   batch = (const int*)d_in[4];
    const float* We[2]    = {(const float*)d_in[5],  (const float*)d_in[13]};
    const float* be[2]    = {(const float*)d_in[6],  (const float*)d_in[14]};
    const float* Wpre[2]  = {(const float*)d_in[7],  (const float*)d_in[15]};
    const float* bpre[2]  = {(const float*)d_in[8],  (const float*)d_in[16]};
    const float* Wpost[2] = {(const float*)d_in[9],  (const float*)d_in[17]};
    const float* bpost[2] = {(const float*)d_in[10], (const float*)d_in[18]};
    const float* Wlin[2]  = {(const float*)d_in[11], (const float*)d_in[19]};
    const float* blin[2]  = {(const float*)d_in[12], (const float*)d_in[20]};
    const float* W1 = (const float*)d_in[21]; const float* b1 = (const float*)d_in[22];
    const float* W2 = (const float*)d_in[23]; const float* b2 = (const float*)d_in[24];
    const float* W3 = (const float*)d_in[25]; const float* b3 = (const float*)d_in[26];
    float* out = (float*)d_out;

    char* ws = (char*)d_ws;
    size_t off_b = 0;
    auto carve = [&](size_t bytes) -> char* {
        char* p = ws + off_b;
        off_b = (off_b + bytes + 255) & ~(size_t)255;
        return p;
    };
    int*      cnt     = (int*)carve((size_t)NN * 4);
    int*      cnt2    = (int*)carve((size_t)NN * 4);
    int*      off     = (int*)carve((size_t)NN * 4);
    int*      sums    = (int*)carve(256 * 4);
    float4*   csr     = (float4*)carve((size_t)EE * 16);          // compact CSR, 12.8 MB
    float*    ABa     = (float*)carve((size_t)NN * 128 * 4);      // fp32 dst-projection
    ushort_t* ABb     = (ushort_t*)carve((size_t)NN * 128 * 2);   // bf16 src-projection
    ushort_t* agg_b   = (ushort_t*)carve((size_t)NN * 512 * 2);   // bf16 agg
    float2*   sc      = (float2*)carve((size_t)NN * 8);
    ushort_t* xs_b    = (ushort_t*)carve((size_t)NN * 32 * 2);
    float*    h1      = (float*)carve((size_t)NN * 64 * 4);
    ushort_t* h1_b    = (ushort_t*)carve((size_t)NN * 64 * 2);
    float*    U       = (float*)carve(256 * 4);
    float*    Wab     = (float*)carve(16384 * 4);
    float*    bias_ab = (float*)carve(256 * 4);
    ushort_t* Bh      = (ushort_t*)carve((size_t)192 * 576 * 2);
    ushort_t* Bl      = (ushort_t*)carve((size_t)192 * 576 * 2);
    float*    bias_zf = (float*)carve(64 * 4);
    float*    pool    = (float*)carve(64 * 64 * 4);

    const int MB128 = (NN + 127) / 128;  // 391
    const int MB64  = (NN + 63) / 64;    // 782
    const int SMEM_ZF = (64 * 40 + 192 * 40 + 192 * 40) * 2;  // 35840

    init_kernel<<<(NN * 32 + 255) / 256, 256, 0, stream>>>(cnt, cnt2, pool, x, xs_b);
    hist_kernel<<<(EE + 255) / 256, 256, 0, stream>>>(eidx, cnt);
    scan_part<<<NB, 256, 0, stream>>>(cnt, sums);
    scan_top<<<1, 256, 0, stream>>>(sums);
    scan_final<<<NB, 256, 0, stream>>>(cnt, sums, off);
    fill_csr<<<(EE + 255) / 256, 256, 0, stream>>>(eidx, eattr, off, cnt2, csr);

    // ---------------- layer 0 (F=32, TF=64, KT=288) ----------------
    prep_ab<32><<<1, 256, 0, stream>>>(We[0], be[0], Wpre[0], bpre[0], U, Wab, bias_ab);
    prep_zf<32><<<12, 256, 0, stream>>>(Wpost[0], Wlin[0], bpost[0], blin[0], Bh, Bl, bias_zf);
    gemm_bias<<<dim3(MB128, 2), 256, 0, stream>>>(x, Wab, bias_ab, ABa, ABb, NN, 32, 128, 64);
    aggregate<32><<<(NN + 3) / 4, 256, 0, stream>>>(ABa, ABb, cnt, off, csr, U, agg_b, sc);
    gemm_zf<32, false><<<MB64, 256, SMEM_ZF, stream>>>(xs_b, agg_b, Bh, Bl, bias_zf, sc,
                                                       h1, h1_b, batch, pool);

    // ---------------- layer 1 (F=64, TF=128, KT=576) ----------------
    prep_ab<64><<<1, 256, 0, stream>>>(We[1], be[1], Wpre[1], bpre[1], U, Wab, bias_ab);
    prep_zf<64><<<12, 256, 0, stream>>>(Wpost[1], Wlin[1], bpost[1], blin[1], Bh, Bl, bias_zf);
    gemm_bias<<<dim3(MB128, 4), 256, 0, stream>>>(h1, Wab, bias_ab, ABa, ABb, NN, 64, 256, 128);
    aggregate<64><<<(NN + 3) / 4, 256, 0, stream>>>(ABa, ABb, cnt, off, csr, U, agg_b, sc);
    gemm_zf<64, true><<<MB64, 256, SMEM_ZF, stream>>>(h1_b, agg_b, Bh, Bl, bias_zf, sc,
                                                      nullptr, nullptr, batch, pool);

    // ---------------- head ----------------
    head_kernel<<<1, 256, 0, stream>>>(pool, hls, W1, b1, W2, b2, W3, b3, out);
}

// Round 12
// 519.759 us; speedup vs baseline: 1.0432x; 1.0432x over previous
//
#include <hip/hip_runtime.h>
#include <math.h>
#include <float.h>

// Problem constants (HierNet_55705725829422)
#define NN 50000      // nodes
#define EE 800000     // edges
#define CAP 64        // max in-degree capacity (Poisson(16): P(>=64) ~ 1e-19)

typedef unsigned short ushort_t;
typedef short short8 __attribute__((ext_vector_type(8)));
typedef float floatx4 __attribute__((ext_vector_type(4)));
typedef float vfloat4 __attribute__((ext_vector_type(4)));  // native vec for nontemporal builtins

__device__ __constant__ float kAVG_LOG = 2.8332133440562162f; // log(17)

__device__ inline ushort_t f2bf(float v) {
    union { float f; unsigned u; } x; x.f = v;
    unsigned r = x.u + 0x7fffu + ((x.u >> 16) & 1u);
    return (ushort_t)(r >> 16);
}
__device__ inline float bf2f(ushort_t b) {
    union { unsigned u; float f; } x; x.u = ((unsigned)b) << 16; return x.f;
}
__device__ inline float bitsf(unsigned u) {
    union { unsigned u; float f; } x; x.u = u; return x.f;
}
__device__ inline void splitbf(float v, ushort_t& hi, ushort_t& lo) {
    hi = f2bf(v);
    lo = f2bf(v - bf2f(hi));
}

// merged init: zero cnt+pool, cast x -> bf16
__global__ __launch_bounds__(256) void init_kernel(int* cnt, float* pool, const float* __restrict__ x,
                                                   ushort_t* __restrict__ xb) {
    int i = blockIdx.x * 256 + threadIdx.x;
    if (i < NN * 32) xb[i] = f2bf(x[i]);
    if (i < NN) cnt[i] = 0;
    if (i < 64 * 64) pool[i] = 0.f;
}

// CSR build: CAP-padded buckets, packed 16B entries {src_bits, ea.x, ea.y, pad},
// 1 edge/thread (occupancy per R10 post-mortem), nontemporal store (write-once region).
__global__ __launch_bounds__(256) void build_csr(const int* __restrict__ ei, const float* __restrict__ ea,
                                                 int* __restrict__ cnt, float4* __restrict__ csr) {
    int e = blockIdx.x * 256 + threadIdx.x;
    if (e >= EE) return;
    int s = ei[e];
    int d = ei[EE + e];
    float2 v = *(const float2*)(ea + 2 * e);
    int p = atomicAdd(&cnt[d], 1);
    if (p < CAP) {
        vfloat4 w = {bitsf((unsigned)s), v.x, v.y, 0.f};
        __builtin_nontemporal_store(w, (vfloat4*)&csr[d * CAP + p]);
    }
}

// per-layer A/B-projection weight prep: U, Wab (fp32), bias_ab
template <int F>
__global__ __launch_bounds__(256) void prep_ab(const float* __restrict__ We, const float* __restrict__ be,
                                               const float* __restrict__ Wpre, const float* __restrict__ bpre,
                                               float* __restrict__ U, float* __restrict__ Wab,
                                               float* __restrict__ bias_ab) {
    const int TF = 2 * F;
    int tid = threadIdx.x;
    for (int idx = tid; idx < 2 * TF; idx += 256) {
        int c = idx / TF, f = idx % TF;
        int t = f / F, o = f % F;
        float s = 0.f;
        for (int g = 0; g < F; ++g)
            s += We[c * F + g] * Wpre[((size_t)t * 3 * F + 2 * F + g) * F + o];
        U[idx] = s;
    }
    for (int idx = tid; idx < F * 2 * TF; idx += 256) {
        int g = idx / (2 * TF), cc = idx % (2 * TF);
        int t, o, row;
        if (cc < TF) { t = cc / F; o = cc % F; row = g; }
        else { int c2 = cc - TF; t = c2 / F; o = c2 % F; row = F + g; }
        Wab[idx] = Wpre[((size_t)t * 3 * F + row) * F + o];
    }
    for (int cc = tid; cc < 2 * TF; cc += 256) {
        float v = 0.f;
        if (cc < TF) {
            int t = cc / F, o = cc % F;
            float s = 0.f;
            for (int g = 0; g < F; ++g)
                s += be[g] * Wpre[((size_t)t * 3 * F + 2 * F + g) * F + o];
            v = s + bpre[t * F + o];
        }
        bias_ab[cc] = v;
    }
}

// Folded Z/final weights, split to bf16 hi/lo, stored COL-MAJOR [192 cols][KT]
template <int F>
__global__ __launch_bounds__(256) void prep_zf(const float* __restrict__ Wpost, const float* __restrict__ Wlin,
                                               const float* __restrict__ bpost, const float* __restrict__ blin,
                                               ushort_t* __restrict__ Bh, ushort_t* __restrict__ Bl,
                                               float* __restrict__ bias_zf) {
    const int KT = 9 * F;
    int bx = blockIdx.x;  // 12 blocks x 16 cols
    int tid = threadIdx.x;
    for (int idx = tid; idx < 16 * KT; idx += 256) {
        int jj = idx / KT, k = idx % KT;
        int jg = bx * 16 + jj;
        int b = jg >> 6, j = jg & 63;
        float v = 0.f;
        if (k < F) {
            if (b == 0) {
                float s = 0.f;
                for (int t = 0; t < 2; ++t)
                    for (int c = 0; c < 32; ++c)
                        s += Wpost[((size_t)t * 13 * F + k) * 32 + c] * Wlin[(t * 32 + c) * 64 + j];
                v = s;
            }
        } else {
            int r = k - F;
            int t = r / (4 * F), rr = r - t * 4 * F;
            float s = 0.f;
            for (int c = 0; c < 32; ++c)
                s += Wpost[((size_t)t * 13 * F + F + b * 4 * F + rr) * 32 + c] * Wlin[(t * 32 + c) * 64 + j];
            v = s;
        }
        ushort_t h_, l_;
        splitbf(v, h_, l_);
        Bh[(size_t)jg * KT + k] = h_;
        Bl[(size_t)jg * KT + k] = l_;
    }
    if (bx == 0) {
        for (int j = tid; j < 64; j += 256) {
            float s = blin[j];
            for (int t = 0; t < 2; ++t)
                for (int c = 0; c < 32; ++c)
                    s += bpost[t * 32 + c] * Wlin[(t * 32 + c) * 64 + j];
            bias_zf[j] = s;
        }
    }
}

// fp32 GEMM: [Ca | Cb] = A[MxK]@B[KxN] + bias. Columns < bstart -> fp32 Ca; >= bstart -> bf16 Cb.
__global__ __launch_bounds__(256) void gemm_bias(const float* __restrict__ A, const float* __restrict__ B,
                                                 const float* __restrict__ bias, float* __restrict__ Ca,
                                                 ushort_t* __restrict__ Cb, int M, int K, int Ncols, int bstart) {
    __shared__ float As[32][132];
    __shared__ float Bs[32][68];
    int m0 = blockIdx.x * 128, c0 = blockIdx.y * 64;
    int tid = threadIdx.x;
    int tx = tid & 15, ty = tid >> 4;
    int ms = tid >> 3, u = tid & 7;
    float acc[8][4] = {};
    for (int k0 = 0; k0 < K; k0 += 32) {
#pragma unroll
        for (int p = 0; p < 4; ++p) {
            int m = ms + 32 * p;
            int gm = m0 + m;
            float4 v = make_float4(0.f, 0.f, 0.f, 0.f);
            if (gm < M) v = *(const float4*)(A + (size_t)gm * K + k0 + u * 4);
            As[u * 4 + 0][m] = v.x; As[u * 4 + 1][m] = v.y;
            As[u * 4 + 2][m] = v.z; As[u * 4 + 3][m] = v.w;
        }
#pragma unroll
        for (int p = 0; p < 2; ++p) {
            int idx = tid + 256 * p;
            int kk = idx >> 4, q = idx & 15;
            *(float4*)&Bs[kk][q * 4] = *(const float4*)(B + (size_t)(k0 + kk) * Ncols + c0 + q * 4);
        }
        __syncthreads();
#pragma unroll 8
        for (int k = 0; k < 32; ++k) {
            float a0[8], b0[4];
            *(float4*)&a0[0] = *(const float4*)&As[k][ty * 8];
            *(float4*)&a0[4] = *(const float4*)&As[k][ty * 8 + 4];
            *(float4*)&b0[0] = *(const float4*)&Bs[k][tx * 4];
#pragma unroll
            for (int i = 0; i < 8; ++i)
#pragma unroll
                for (int j = 0; j < 4; ++j) acc[i][j] = fmaf(a0[i], b0[j], acc[i][j]);
        }
        __syncthreads();
    }
    float bj[4];
#pragma unroll
    for (int j = 0; j < 4; ++j) bj[j] = bias[c0 + tx * 4 + j];
    bool bside = (c0 >= bstart);
    int TFw = bstart;  // row stride of both halves
#pragma unroll
    for (int i = 0; i < 8; ++i) {
        int gm = m0 + ty * 8 + i;
        if (gm >= M) continue;
        float v0 = acc[i][0] + bj[0], v1 = acc[i][1] + bj[1];
        float v2 = acc[i][2] + bj[2], v3 = acc[i][3] + bj[3];
        if (!bside) {
            *(float4*)(Ca + (size_t)gm * TFw + c0 + tx * 4) = make_float4(v0, v1, v2, v3);
        } else {
            ushort4 w;
            w.x = f2bf(v0); w.y = f2bf(v1); w.z = f2bf(v2); w.w = f2bf(v3);
            *(ushort4*)(Cb + (size_t)gm * TFw + (c0 - bstart) + tx * 4) = w;
        }
    }
}

// aggregate: ONE wave per node, CAP-padded CSR, SCALARIZED entry loads (wave-uniform
// address via readfirstlane -> s_load_dwordx4, no shfl broadcasts), bf16 gather.
template <int F>
__global__ __launch_bounds__(256) void aggregate(const float* __restrict__ ABa, const ushort_t* __restrict__ ABb,
                                                 const int* __restrict__ cnt, const float4* __restrict__ csr,
                                                 const float* __restrict__ U,
                                                 ushort_t* __restrict__ agg_b, float2* __restrict__ sc) {
    const int TF = 2 * F;
    const int FPL = TF / 64;  // 1 (F=32) or 2 (F=64)
    int lane = threadIdx.x & 63;
    int n = blockIdx.x * 4 + (threadIdx.x >> 6);
    if (n >= NN) return;
    n = __builtin_amdgcn_readfirstlane(n);  // force wave-uniform -> scalar loads below
    int f0 = FPL * lane;

    float base[FPL], u0[FPL], u1[FPL], sum[FPL], sq[FPL], mn[FPL], mx[FPL];
#pragma unroll
    for (int r = 0; r < FPL; ++r) {
        base[r] = ABa[(size_t)n * TF + f0 + r];
        u0[r] = U[f0 + r];
        u1[r] = U[TF + f0 + r];
        sum[r] = 0.f; sq[r] = 0.f; mn[r] = FLT_MAX; mx[r] = -FLT_MAX;
    }
    int deg = cnt[n];
    int ec = deg < CAP ? deg : CAP;
    if (ec > 0) {
        const float4* eb = csr + n * CAP;
        for (int e = 0; e < ec; e += 8) {
            float4 ent[8];
#pragma unroll
            for (int i = 0; i < 8; ++i)
                if (e + i < ec) ent[i] = eb[e + i];  // uniform addr -> s_load_dwordx4
            unsigned wv[8];
#pragma unroll
            for (int i = 0; i < 8; ++i) {
                if (e + i < ec) {
                    int sb = __float_as_int(ent[i].x);
                    if constexpr (FPL == 2)
                        wv[i] = *(const unsigned*)(ABb + (size_t)sb * TF + f0);
                    else
                        wv[i] = ABb[(size_t)sb * TF + f0];
                }
            }
#pragma unroll
            for (int i = 0; i < 8; ++i) {
                if (e + i < ec) {
                    float ex = ent[i].y, ey = ent[i].z;
                    float v[FPL];
                    if constexpr (FPL == 2) {
                        v[0] = bitsf(wv[i] << 16);
                        v[1] = bitsf(wv[i] & 0xffff0000u);
                    } else {
                        v[0] = bitsf(wv[i] << 16);
                    }
#pragma unroll
                    for (int r = 0; r < FPL; ++r) {
                        float q = fmaf(ex, u0[r], fmaf(ey, u1[r], v[r]));
                        sum[r] += q;
                        sq[r] = fmaf(q, q, sq[r]);
                        mn[r] = fminf(mn[r], q);
                        mx[r] = fmaxf(mx[r], q);
                    }
                }
            }
        }
    }
    float d = (float)(deg > 1 ? deg : 1);
    float inv_d = 1.f / d;
    bool has = deg > 0;
#pragma unroll
    for (int r = 0; r < FPL; ++r) {
        float mean_q = sum[r] * inv_d;
        float var = sq[r] * inv_d - mean_q * mean_q;
        float stdv = sqrtf(fmaxf(var, 0.f) + 1e-5f);
        float mean = has ? base[r] + mean_q : 0.f;
        float vmn = has ? base[r] + mn[r] : 0.f;
        float vmx = has ? base[r] + mx[r] : 0.f;
        int f = f0 + r;
        int t = f / F, o = f - t * F;
        size_t rowb = (size_t)n * (4 * TF) + (size_t)t * (4 * F);
        agg_b[rowb + o] = f2bf(mean);
        agg_b[rowb + F + o] = f2bf(vmn);
        agg_b[rowb + 2 * F + o] = f2bf(vmx);
        agg_b[rowb + 3 * F + o] = f2bf(stdv);
    }
    if (lane == 0) {
        float logd = logf(d + 1.f);
        sc[n] = make_float2(logd / kAVG_LOG, kAVG_LOG / logd);
    }
}

// MFMA merged Z+final GEMM. A bf16 (single), B split hi/lo: Y = Ah@Bh + Ah@Bl.
// Block 64 rows x 192 cols; wave w owns col-frags {w, w+4, w+8} x 4 row-frags.
// Register-prefetch pipeline: k0+1 global loads issued before k0's MFMA block.
template <int F, bool POOL>
__global__ __launch_bounds__(256) void gemm_zf(
    const ushort_t* __restrict__ xs_b, const ushort_t* __restrict__ agg_b,
    const ushort_t* __restrict__ Bh, const ushort_t* __restrict__ Bl,
    const float* __restrict__ bias_zf, const float2* __restrict__ sc,
    float* __restrict__ H, ushort_t* __restrict__ H_b,
    const int* __restrict__ batch, float* __restrict__ pool) {
    const int KT = 9 * F;
    extern __shared__ char smem[];
    ushort_t* A_s  = (ushort_t*)smem;        // [64][40]
    ushort_t* Bh_s = A_s + 64 * 40;          // [192][40]
    ushort_t* Bl_s = Bh_s + 192 * 40;        // [192][40]
    float* hbuf = (float*)smem;              // POOL alias [64][68]

    int m0 = blockIdx.x * 64;
    int tid = threadIdx.x;
    int lane = tid & 63;
    int wave = tid >> 6;
    int ln = lane & 15, quad = lane >> 4;

    floatx4 acc[4][3];
#pragma unroll
    for (int i = 0; i < 4; ++i)
#pragma unroll
        for (int j = 0; j < 3; ++j) acc[i][j] = (floatx4)(0.f);

    int arow = tid >> 2, asg = tid & 3;
    int agm = m0 + arow;
    int bcol[3], bsg[3];
#pragma unroll
    for (int p = 0; p < 3; ++p) {
        int idx = tid + 256 * p;
        bcol[p] = idx >> 2;
        bsg[p] = idx & 3;
    }

    const short8 zero8 = {0, 0, 0, 0, 0, 0, 0, 0};
    short8 pa, pbh[3], pbl[3];
    // prefetch k0 = 0
    {
        int c0 = asg * 8;  // always < F at k0=0
        pa = zero8;
        if (agm < NN) pa = *(const short8*)(xs_b + (size_t)agm * F + c0);
#pragma unroll
        for (int p = 0; p < 3; ++p) {
            pbh[p] = *(const short8*)(Bh + (size_t)bcol[p] * KT + bsg[p] * 8);
            pbl[p] = *(const short8*)(Bl + (size_t)bcol[p] * KT + bsg[p] * 8);
        }
    }

    for (int k0 = 0; k0 < KT; k0 += 32) {
        // write staged regs -> LDS
        *(short8*)&A_s[arow * 40 + asg * 8] = pa;
#pragma unroll
        for (int p = 0; p < 3; ++p) {
            *(short8*)&Bh_s[bcol[p] * 40 + bsg[p] * 8] = pbh[p];
            *(short8*)&Bl_s[bcol[p] * 40 + bsg[p] * 8] = pbl[p];
        }
        __syncthreads();
        short8 ah[4], bh[3], bl[3];
#pragma unroll
        for (int rf = 0; rf < 4; ++rf)
            ah[rf] = *(short8*)&A_s[(rf * 16 + ln) * 40 + quad * 8];
#pragma unroll
        for (int b = 0; b < 3; ++b) {
            int col = b * 64 + wave * 16 + ln;
            bh[b] = *(short8*)&Bh_s[col * 40 + quad * 8];
            bl[b] = *(short8*)&Bl_s[col * 40 + quad * 8];
        }
        // issue next-k0 global loads (overlap with MFMA below)
        int kn = k0 + 32;
        if (kn < KT) {
            int c0 = kn + asg * 8;
            pa = zero8;
            if (agm < NN) {
                pa = (c0 < F) ? *(const short8*)(xs_b + (size_t)agm * F + c0)
                              : *(const short8*)(agg_b + (size_t)agm * 8 * F + (c0 - F));
            }
#pragma unroll
            for (int p = 0; p < 3; ++p) {
                pbh[p] = *(const short8*)(Bh + (size_t)bcol[p] * KT + kn + bsg[p] * 8);
                pbl[p] = *(const short8*)(Bl + (size_t)bcol[p] * KT + kn + bsg[p] * 8);
            }
        }
#pragma unroll
        for (int rf = 0; rf < 4; ++rf)
#pragma unroll
            for (int b = 0; b < 3; ++b) {
                acc[rf][b] = __builtin_amdgcn_mfma_f32_16x16x32_bf16(ah[rf], bh[b], acc[rf][b], 0, 0, 0);
                acc[rf][b] = __builtin_amdgcn_mfma_f32_16x16x32_bf16(ah[rf], bl[b], acc[rf][b], 0, 0, 0);
            }
        __syncthreads();
    }

    int ocol = wave * 16 + ln;  // output col 0..63
    float bcolv = bias_zf[ocol];

#pragma unroll
    for (int rf = 0; rf < 4; ++rf) {
#pragma unroll
        for (int reg = 0; reg < 4; ++reg) {
            int r = rf * 16 + quad * 4 + reg;
            int gm = m0 + r;
            float2 s = make_float2(0.f, 0.f);
            if (gm < NN) s = sc[gm];
            float y = acc[rf][0][reg] + s.x * acc[rf][1][reg] + s.y * acc[rf][2][reg] + bcolv;
            y = fmaxf(y, 0.f);
            if (POOL) {
                hbuf[r * 68 + ocol] = (gm < NN) ? y : 0.f;
            } else if (gm < NN) {
                H[(size_t)gm * 64 + ocol] = y;
                H_b[(size_t)gm * 64 + ocol] = f2bf(y);
            }
        }
    }
    if (POOL) {
        __syncthreads();
        int col = tid & 63, grp = tid >> 6;
        float a = 0.f;
        int cur = -1;
        for (int i = 0; i < 16; ++i) {
            int r = grp * 16 + i;
            int gm = m0 + r;
            if (gm >= NN) break;
            int b = batch[gm];
            if (b != cur) {
                if (cur >= 0) atomicAdd(&pool[cur * 64 + col], a);
                cur = b; a = 0.f;
            }
            a += hbuf[r * 68 + col];
        }
        if (cur >= 0) atomicAdd(&pool[cur * 64 + col], a);
    }
}

__global__ __launch_bounds__(256) void head_kernel(const float* __restrict__ gpool, const float* __restrict__ hls,
                                                   const float* __restrict__ W1, const float* __restrict__ b1,
                                                   const float* __restrict__ W2, const float* __restrict__ b2,
                                                   const float* __restrict__ W3, const float* __restrict__ b3,
                                                   float* __restrict__ out) {
    __shared__ float gin[64][96];
    __shared__ float r1[64][64];
    __shared__ float r2[64][64];
    int tid = threadIdx.x;
    for (int idx = tid; idx < 64 * 96; idx += 256) {
        int g = idx / 96, j = idx % 96;
        gin[g][j] = (j < 64) ? gpool[g * 64 + j] : hls[g * 32 + (j - 64)];
    }
    __syncthreads();
    for (int idx = tid; idx < 64 * 64; idx += 256) {
        int g = idx / 64, j = idx % 64;
        float acc = b1[j];
        for (int k = 0; k < 96; ++k) acc = fmaf(gin[g][k], W1[k * 64 + j], acc);
        r1[g][j] = fmaxf(acc, 0.f);
    }
    __syncthreads();
    for (int idx = tid; idx < 64 * 64; idx += 256) {
        int g = idx / 64, j = idx % 64;
        float acc = b2[j];
        for (int k = 0; k < 64; ++k) acc = fmaf(r1[g][k], W2[k * 64 + j], acc);
        r2[g][j] = fmaxf(acc, 0.f);
    }
    __syncthreads();
    if (tid < 64) {
        float acc = b3[0];
        for (int k = 0; k < 64; ++k) acc = fmaf(r2[tid][k], W3[k], acc);
        out[tid] = acc;
    }
}

extern "C" void kernel_launch(void* const* d_in, const int* in_sizes, int n_in,
                              void* d_out, int out_size, void* d_ws, size_t ws_size,
                              hipStream_t stream) {
    (void)in_sizes; (void)n_in; (void)out_size; (void)ws_size;
    const float* x     = (const float*)d_in[0];
    const float* eattr = (const float*)d_in[1];
    const float* hls   = (const float*)d_in[2];
    const int*   eidx  = (const int*)d_in[3];
    const int*   batch = (const int*)d_in[4];
    const float* We[2]    = {(const float*)d_in[5],  (const float*)d_in[13]};
    const float* be[2]    = {(const float*)d_in[6],  (const float*)d_in[14]};
    const float* Wpre[2]  = {(const float*)d_in[7],  (const float*)d_in[15]};
    const float* bpre[2]  = {(const float*)d_in[8],  (const float*)d_in[16]};
    const float* Wpost[2] = {(const float*)d_in[9],  (const float*)d_in[17]};
    const float* bpost[2] = {(const float*)d_in[10], (const float*)d_in[18]};
    const float* Wlin[2]  = {(const float*)d_in[11], (const float*)d_in[19]};
    const float* blin[2]  = {(const float*)d_in[12], (const float*)d_in[20]};
    const float* W1 = (const float*)d_in[21]; const float* b1 = (const float*)d_in[22];
    const float* W2 = (const float*)d_in[23]; const float* b2 = (const float*)d_in[24];
    const float* W3 = (const float*)d_in[25]; const float* b3 = (const float*)d_in[26];
    float* out = (float*)d_out;

    char* ws = (char*)d_ws;
    size_t off = 0;
    auto carve = [&](size_t bytes) -> char* {
        char* p = ws + off;
        off = (off + bytes + 255) & ~(size_t)255;
        return p;
    };
    int*      cnt     = (int*)carve((size_t)NN * 4);
    float4*   csr     = (float4*)carve((size_t)NN * CAP * 16);
    float*    ABa     = (float*)carve((size_t)NN * 128 * 4);      // fp32 dst-projection
    ushort_t* ABb     = (ushort_t*)carve((size_t)NN * 128 * 2);   // bf16 src-projection
    ushort_t* agg_b   = (ushort_t*)carve((size_t)NN * 512 * 2);   // bf16 agg
    float2*   sc      = (float2*)carve((size_t)NN * 8);
    ushort_t* xs_b    = (ushort_t*)carve((size_t)NN * 32 * 2);
    float*    h1      = (float*)carve((size_t)NN * 64 * 4);
    ushort_t* h1_b    = (ushort_t*)carve((size_t)NN * 64 * 2);
    float*    U       = (float*)carve(256 * 4);
    float*    Wab     = (float*)carve(16384 * 4);
    float*    bias_ab = (float*)carve(256 * 4);
    ushort_t* Bh      = (ushort_t*)carve((size_t)192 * 576 * 2);
    ushort_t* Bl      = (ushort_t*)carve((size_t)192 * 576 * 2);
    float*    bias_zf = (float*)carve(64 * 4);
    float*    pool    = (float*)carve(64 * 64 * 4);

    const int MB128 = (NN + 127) / 128;  // 391
    const int MB64  = (NN + 63) / 64;    // 782
    const int SMEM_ZF = (64 * 40 + 192 * 40 + 192 * 40) * 2;  // 35840

    init_kernel<<<(NN * 32 + 255) / 256, 256, 0, stream>>>(cnt, pool, x, xs_b);
    build_csr<<<(EE + 255) / 256, 256, 0, stream>>>(eidx, eattr, cnt, csr);

    // ---------------- layer 0 (F=32, TF=64, KT=288) ----------------
    prep_ab<32><<<1, 256, 0, stream>>>(We[0], be[0], Wpre[0], bpre[0], U, Wab, bias_ab);
    prep_zf<32><<<12, 256, 0, stream>>>(Wpost[0], Wlin[0], bpost[0], blin[0], Bh, Bl, bias_zf);
    gemm_bias<<<dim3(MB128, 2), 256, 0, stream>>>(x, Wab, bias_ab, ABa, ABb, NN, 32, 128, 64);
    aggregate<32><<<(NN + 3) / 4, 256, 0, stream>>>(ABa, ABb, cnt, csr, U, agg_b, sc);
    gemm_zf<32, false><<<MB64, 256, SMEM_ZF, stream>>>(xs_b, agg_b, Bh, Bl, bias_zf, sc,
                                                       h1, h1_b, batch, pool);

    // ---------------- layer 1 (F=64, TF=128, KT=576) ----------------
    prep_ab<64><<<1, 256, 0, stream>>>(We[1], be[1], Wpre[1], bpre[1], U, Wab, bias_ab);
    prep_zf<64><<<12, 256, 0, stream>>>(Wpost[1], Wlin[1], bpost[1], blin[1], Bh, Bl, bias_zf);
    gemm_bias<<<dim3(MB128, 4), 256, 0, stream>>>(h1, Wab, bias_ab, ABa, ABb, NN, 64, 256, 128);
    aggregate<64><<<(NN + 3) / 4, 256, 0, stream>>>(ABa, ABb, cnt, csr, U, agg_b, sc);
    gemm_zf<64, true><<<MB64, 256, SMEM_ZF, stream>>>(h1_b, agg_b, Bh, Bl, bias_zf, sc,
                                                      nullptr, nullptr, batch, pool);

    // ---------------- head ----------------
    head_kernel<<<1, 256, 0, stream>>>(pool, hls, W1, b1, W2, b2, W3, b3, out);
}

// Round 13
// 436.298 us; speedup vs baseline: 1.2428x; 1.1913x over previous
//
#include <hip/hip_runtime.h>
#include <math.h>
#include <float.h>

// Problem constants (HierNet_55705725829422)
#define NN 50000      // nodes
#define EE 800000     // edges
#define CAP 64        // max in-degree capacity (Poisson(16): P(>=64) ~ 1e-19)

typedef unsigned short ushort_t;
typedef short short8 __attribute__((ext_vector_type(8)));
typedef float floatx4 __attribute__((ext_vector_type(4)));
typedef float vfloat4 __attribute__((ext_vector_type(4)));

__device__ __constant__ float kAVG_LOG = 2.8332133440562162f; // log(17)

__device__ inline ushort_t f2bf(float v) {
    union { float f; unsigned u; } x; x.f = v;
    unsigned r = x.u + 0x7fffu + ((x.u >> 16) & 1u);
    return (ushort_t)(r >> 16);
}
__device__ inline float bf2f(ushort_t b) {
    union { unsigned u; float f; } x; x.u = ((unsigned)b) << 16; return x.f;
}
__device__ inline float bitsf(unsigned u) {
    union { unsigned u; float f; } x; x.u = u; return x.f;
}
__device__ inline void splitbf(float v, ushort_t& hi, ushort_t& lo) {
    hi = f2bf(v);
    lo = f2bf(v - bf2f(hi));
}

// merged init: zero cnt+pool, cast x -> bf16
__global__ __launch_bounds__(256) void init_kernel(int* cnt, float* pool, const float* __restrict__ x,
                                                   ushort_t* __restrict__ xb) {
    int i = blockIdx.x * 256 + threadIdx.x;
    if (i < NN * 32) xb[i] = f2bf(x[i]);
    if (i < NN) cnt[i] = 0;
    if (i < 64 * 64) pool[i] = 0.f;
}

// CSR build: CAP-padded buckets, packed 16B entries, 1 edge/thread, nt store.
__global__ __launch_bounds__(256) void build_csr(const int* __restrict__ ei, const float* __restrict__ ea,
                                                 int* __restrict__ cnt, float4* __restrict__ csr) {
    int e = blockIdx.x * 256 + threadIdx.x;
    if (e >= EE) return;
    int s = ei[e];
    int d = ei[EE + e];
    float2 v = *(const float2*)(ea + 2 * e);
    int p = atomicAdd(&cnt[d], 1);
    if (p < CAP) {
        vfloat4 w = {bitsf((unsigned)s), v.x, v.y, 0.f};
        __builtin_nontemporal_store(w, (vfloat4*)&csr[d * CAP + p]);
    }
}

// ---------------- fused weight prep (one launch, blockIdx dispatch) ----------------
template <int F>
__device__ void prep_ab_dev(const float* __restrict__ We, const float* __restrict__ be,
                            const float* __restrict__ Wpre, const float* __restrict__ bpre,
                            float* __restrict__ U, float* __restrict__ Wab,
                            float* __restrict__ bias_ab) {
    const int TF = 2 * F;
    int tid = threadIdx.x;
    for (int idx = tid; idx < 2 * TF; idx += 256) {
        int c = idx / TF, f = idx % TF;
        int t = f / F, o = f % F;
        float s = 0.f;
        for (int g = 0; g < F; ++g)
            s += We[c * F + g] * Wpre[((size_t)t * 3 * F + 2 * F + g) * F + o];
        U[idx] = s;
    }
    for (int idx = tid; idx < F * 2 * TF; idx += 256) {
        int g = idx / (2 * TF), cc = idx % (2 * TF);
        int t, o, row;
        if (cc < TF) { t = cc / F; o = cc % F; row = g; }
        else { int c2 = cc - TF; t = c2 / F; o = c2 % F; row = F + g; }
        Wab[idx] = Wpre[((size_t)t * 3 * F + row) * F + o];
    }
    for (int cc = tid; cc < 2 * TF; cc += 256) {
        float v = 0.f;
        if (cc < TF) {
            int t = cc / F, o = cc % F;
            float s = 0.f;
            for (int g = 0; g < F; ++g)
                s += be[g] * Wpre[((size_t)t * 3 * F + 2 * F + g) * F + o];
            v = s + bpre[t * F + o];
        }
        bias_ab[cc] = v;
    }
}

template <int F>
__device__ void prep_zf_dev(int bx, const float* __restrict__ Wpost, const float* __restrict__ Wlin,
                            const float* __restrict__ bpost, const float* __restrict__ blin,
                            ushort_t* __restrict__ Bh, ushort_t* __restrict__ Bl,
                            float* __restrict__ bias_zf) {
    const int KT = 9 * F;
    int tid = threadIdx.x;
    for (int idx = tid; idx < 16 * KT; idx += 256) {
        int jj = idx / KT, k = idx % KT;
        int jg = bx * 16 + jj;
        int b = jg >> 6, j = jg & 63;
        float v = 0.f;
        if (k < F) {
            if (b == 0) {
                float s = 0.f;
                for (int t = 0; t < 2; ++t)
                    for (int c = 0; c < 32; ++c)
                        s += Wpost[((size_t)t * 13 * F + k) * 32 + c] * Wlin[(t * 32 + c) * 64 + j];
                v = s;
            }
        } else {
            int r = k - F;
            int t = r / (4 * F), rr = r - t * 4 * F;
            float s = 0.f;
            for (int c = 0; c < 32; ++c)
                s += Wpost[((size_t)t * 13 * F + F + b * 4 * F + rr) * 32 + c] * Wlin[(t * 32 + c) * 64 + j];
            v = s;
        }
        ushort_t h_, l_;
        splitbf(v, h_, l_);
        Bh[(size_t)jg * KT + k] = h_;
        Bl[(size_t)jg * KT + k] = l_;
    }
    if (bx == 0) {
        for (int j = tid; j < 64; j += 256) {
            float s = blin[j];
            for (int t = 0; t < 2; ++t)
                for (int c = 0; c < 32; ++c)
                    s += bpost[t * 32 + c] * Wlin[(t * 32 + c) * 64 + j];
            bias_zf[j] = s;
        }
    }
}

__global__ __launch_bounds__(256) void prep_all(
    const float* We0, const float* be0, const float* Wpre0, const float* bpre0,
    const float* Wpost0, const float* Wlin0, const float* bpost0, const float* blin0,
    const float* We1, const float* be1, const float* Wpre1, const float* bpre1,
    const float* Wpost1, const float* Wlin1, const float* bpost1, const float* blin1,
    float* U0, float* Wab0, float* bias_ab0, ushort_t* Bh0, ushort_t* Bl0, float* bias_zf0,
    float* U1, float* Wab1, float* bias_ab1, ushort_t* Bh1, ushort_t* Bl1, float* bias_zf1) {
    int b = blockIdx.x;
    if (b < 12) prep_zf_dev<32>(b, Wpost0, Wlin0, bpost0, blin0, Bh0, Bl0, bias_zf0);
    else if (b < 24) prep_zf_dev<64>(b - 12, Wpost1, Wlin1, bpost1, blin1, Bh1, Bl1, bias_zf1);
    else if (b == 24) prep_ab_dev<32>(We0, be0, Wpre0, bpre0, U0, Wab0, bias_ab0);
    else prep_ab_dev<64>(We1, be1, Wpre1, bpre1, U1, Wab1, bias_ab1);
}

// fp32 GEMM: [Ca | Cb] = A[MxK]@B[KxN] + bias. Columns < bstart -> fp32 Ca; >= bstart -> bf16 Cb.
__global__ __launch_bounds__(256) void gemm_bias(const float* __restrict__ A, const float* __restrict__ B,
                                                 const float* __restrict__ bias, float* __restrict__ Ca,
                                                 ushort_t* __restrict__ Cb, int M, int K, int Ncols, int bstart) {
    __shared__ float As[32][132];
    __shared__ float Bs[32][68];
    int m0 = blockIdx.x * 128, c0 = blockIdx.y * 64;
    int tid = threadIdx.x;
    int tx = tid & 15, ty = tid >> 4;
    int ms = tid >> 3, u = tid & 7;
    float acc[8][4] = {};
    for (int k0 = 0; k0 < K; k0 += 32) {
#pragma unroll
        for (int p = 0; p < 4; ++p) {
            int m = ms + 32 * p;
            int gm = m0 + m;
            float4 v = make_float4(0.f, 0.f, 0.f, 0.f);
            if (gm < M) v = *(const float4*)(A + (size_t)gm * K + k0 + u * 4);
            As[u * 4 + 0][m] = v.x; As[u * 4 + 1][m] = v.y;
            As[u * 4 + 2][m] = v.z; As[u * 4 + 3][m] = v.w;
        }
#pragma unroll
        for (int p = 0; p < 2; ++p) {
            int idx = tid + 256 * p;
            int kk = idx >> 4, q = idx & 15;
            *(float4*)&Bs[kk][q * 4] = *(const float4*)(B + (size_t)(k0 + kk) * Ncols + c0 + q * 4);
        }
        __syncthreads();
#pragma unroll 8
        for (int k = 0; k < 32; ++k) {
            float a0[8], b0[4];
            *(float4*)&a0[0] = *(const float4*)&As[k][ty * 8];
            *(float4*)&a0[4] = *(const float4*)&As[k][ty * 8 + 4];
            *(float4*)&b0[0] = *(const float4*)&Bs[k][tx * 4];
#pragma unroll
            for (int i = 0; i < 8; ++i)
#pragma unroll
                for (int j = 0; j < 4; ++j) acc[i][j] = fmaf(a0[i], b0[j], acc[i][j]);
        }
        __syncthreads();
    }
    float bj[4];
#pragma unroll
    for (int j = 0; j < 4; ++j) bj[j] = bias[c0 + tx * 4 + j];
    bool bside = (c0 >= bstart);
    int TFw = bstart;
#pragma unroll
    for (int i = 0; i < 8; ++i) {
        int gm = m0 + ty * 8 + i;
        if (gm >= M) continue;
        float v0 = acc[i][0] + bj[0], v1 = acc[i][1] + bj[1];
        float v2 = acc[i][2] + bj[2], v3 = acc[i][3] + bj[3];
        if (!bside) {
            *(float4*)(Ca + (size_t)gm * TFw + c0 + tx * 4) = make_float4(v0, v1, v2, v3);
        } else {
            ushort4 w;
            w.x = f2bf(v0); w.y = f2bf(v1); w.z = f2bf(v2); w.w = f2bf(v3);
            *(ushort4*)(Cb + (size_t)gm * TFw + (c0 - bstart) + tx * 4) = w;
        }
    }
}

// aggregate: ONE wave per node, lane-parallel entry load + shfl broadcast (R8 form),
// guard-free 8-edge main chunks + guarded tail. bf16 gather, bf16 agg output.
template <int F>
__global__ __launch_bounds__(256) void aggregate(const float* __restrict__ ABa, const ushort_t* __restrict__ ABb,
                                                 const int* __restrict__ cnt, const float4* __restrict__ csr,
                                                 const float* __restrict__ U,
                                                 ushort_t* __restrict__ agg_b, float2* __restrict__ sc) {
    const int TF = 2 * F;
    const int FPL = TF / 64;  // 1 (F=32) or 2 (F=64)
    int lane = threadIdx.x & 63;
    int n = blockIdx.x * 4 + (threadIdx.x >> 6);
    if (n >= NN) return;
    int f0 = FPL * lane;

    float base[FPL], u0[FPL], u1[FPL], sum[FPL], sq[FPL], mn[FPL], mx[FPL];
#pragma unroll
    for (int r = 0; r < FPL; ++r) {
        base[r] = ABa[(size_t)n * TF + f0 + r];
        u0[r] = U[f0 + r];
        u1[r] = U[TF + f0 + r];
        sum[r] = 0.f; sq[r] = 0.f; mn[r] = FLT_MAX; mx[r] = -FLT_MAX;
    }
    int deg = cnt[n];
    int ec = deg < CAP ? deg : CAP;
    if (ec > 0) {
        int ebase = n * CAP;
        int myi = lane < ec ? lane : ec - 1;
        float4 ent = csr[ebase + myi];
        int msrc = __float_as_int(ent.x);
        float meax = ent.y, meay = ent.z;
        int e = 0;
        // guard-free full chunks (deg ~ Poisson(16): most chunks are full)
        for (; e + 8 <= ec; e += 8) {
            int sb[8]; float ex[8], ey[8];
            unsigned wv[8];
#pragma unroll
            for (int i = 0; i < 8; ++i) {
                sb[i] = __shfl(msrc, e + i);
                ex[i] = __shfl(meax, e + i);
                ey[i] = __shfl(meay, e + i);
            }
#pragma unroll
            for (int i = 0; i < 8; ++i) {
                if constexpr (FPL == 2)
                    wv[i] = *(const unsigned*)(ABb + (size_t)sb[i] * TF + f0);
                else
                    wv[i] = ABb[(size_t)sb[i] * TF + f0];
            }
#pragma unroll
            for (int i = 0; i < 8; ++i) {
                float v[FPL];
                if constexpr (FPL == 2) {
                    v[0] = bitsf(wv[i] << 16);
                    v[1] = bitsf(wv[i] & 0xffff0000u);
                } else {
                    v[0] = bitsf(wv[i] << 16);
                }
#pragma unroll
                for (int r = 0; r < FPL; ++r) {
                    float q = fmaf(ex[i], u0[r], fmaf(ey[i], u1[r], v[r]));
                    sum[r] += q;
                    sq[r] = fmaf(q, q, sq[r]);
                    mn[r] = fminf(mn[r], q);
                    mx[r] = fmaxf(mx[r], q);
                }
            }
        }
        // guarded tail
        if (e < ec) {
            int sb[8]; float ex[8], ey[8];
            unsigned wv[8];
#pragma unroll
            for (int i = 0; i < 8; ++i) {
                sb[i] = __shfl(msrc, e + i);
                ex[i] = __shfl(meax, e + i);
                ey[i] = __shfl(meay, e + i);
            }
#pragma unroll
            for (int i = 0; i < 8; ++i) {
                if (e + i < ec) {
                    if constexpr (FPL == 2)
                        wv[i] = *(const unsigned*)(ABb + (size_t)sb[i] * TF + f0);
                    else
                        wv[i] = ABb[(size_t)sb[i] * TF + f0];
                }
            }
#pragma unroll
            for (int i = 0; i < 8; ++i) {
                if (e + i < ec) {
                    float v[FPL];
                    if constexpr (FPL == 2) {
                        v[0] = bitsf(wv[i] << 16);
                        v[1] = bitsf(wv[i] & 0xffff0000u);
                    } else {
                        v[0] = bitsf(wv[i] << 16);
                    }
#pragma unroll
                    for (int r = 0; r < FPL; ++r) {
                        float q = fmaf(ex[i], u0[r], fmaf(ey[i], u1[r], v[r]));
                        sum[r] += q;
                        sq[r] = fmaf(q, q, sq[r]);
                        mn[r] = fminf(mn[r], q);
                        mx[r] = fmaxf(mx[r], q);
                    }
                }
            }
        }
    }
    float d = (float)(deg > 1 ? deg : 1);
    float inv_d = 1.f / d;
    bool has = deg > 0;
#pragma unroll
    for (int r = 0; r < FPL; ++r) {
        float mean_q = sum[r] * inv_d;
        float var = sq[r] * inv_d - mean_q * mean_q;
        float stdv = sqrtf(fmaxf(var, 0.f) + 1e-5f);
        float mean = has ? base[r] + mean_q : 0.f;
        float vmn = has ? base[r] + mn[r] : 0.f;
        float vmx = has ? base[r] + mx[r] : 0.f;
        int f = f0 + r;
        int t = f / F, o = f - t * F;
        size_t rowb = (size_t)n * (4 * TF) + (size_t)t * (4 * F);
        agg_b[rowb + o] = f2bf(mean);
        agg_b[rowb + F + o] = f2bf(vmn);
        agg_b[rowb + 2 * F + o] = f2bf(vmx);
        agg_b[rowb + 3 * F + o] = f2bf(stdv);
    }
    if (lane == 0) {
        float logd = logf(d + 1.f);
        sc[n] = make_float2(logd / kAVG_LOG, kAVG_LOG / logd);
    }
}

// MFMA merged Z+final GEMM. A bf16 (single), B split hi/lo: Y = Ah@Bh + Ah@Bl.
// Block 64 rows x 192 cols; wave w owns col-frags {w, w+4, w+8} x 4 row-frags.
// Register-prefetch pipeline: k0+1 global loads issued before k0's MFMA block.
template <int F, bool POOL>
__global__ __launch_bounds__(256) void gemm_zf(
    const ushort_t* __restrict__ xs_b, const ushort_t* __restrict__ agg_b,
    const ushort_t* __restrict__ Bh, const ushort_t* __restrict__ Bl,
    const float* __restrict__ bias_zf, const float2* __restrict__ sc,
    float* __restrict__ H, ushort_t* __restrict__ H_b,
    const int* __restrict__ batch, float* __restrict__ pool) {
    const int KT = 9 * F;
    extern __shared__ char smem[];
    ushort_t* A_s  = (ushort_t*)smem;        // [64][40]
    ushort_t* Bh_s = A_s + 64 * 40;          // [192][40]
    ushort_t* Bl_s = Bh_s + 192 * 40;        // [192][40]
    float* hbuf = (float*)smem;              // POOL alias [64][68]

    int m0 = blockIdx.x * 64;
    int tid = threadIdx.x;
    int lane = tid & 63;
    int wave = tid >> 6;
    int ln = lane & 15, quad = lane >> 4;

    floatx4 acc[4][3];
#pragma unroll
    for (int i = 0; i < 4; ++i)
#pragma unroll
        for (int j = 0; j < 3; ++j) acc[i][j] = (floatx4)(0.f);

    int arow = tid >> 2, asg = tid & 3;
    int agm = m0 + arow;
    int bcol[3], bsg[3];
#pragma unroll
    for (int p = 0; p < 3; ++p) {
        int idx = tid + 256 * p;
        bcol[p] = idx >> 2;
        bsg[p] = idx & 3;
    }

    const short8 zero8 = {0, 0, 0, 0, 0, 0, 0, 0};
    short8 pa, pbh[3], pbl[3];
    {
        int c0 = asg * 8;
        pa = zero8;
        if (agm < NN) pa = *(const short8*)(xs_b + (size_t)agm * F + c0);
#pragma unroll
        for (int p = 0; p < 3; ++p) {
            pbh[p] = *(const short8*)(Bh + (size_t)bcol[p] * KT + bsg[p] * 8);
            pbl[p] = *(const short8*)(Bl + (size_t)bcol[p] * KT + bsg[p] * 8);
        }
    }

    for (int k0 = 0; k0 < KT; k0 += 32) {
        *(short8*)&A_s[arow * 40 + asg * 8] = pa;
#pragma unroll
        for (int p = 0; p < 3; ++p) {
            *(short8*)&Bh_s[bcol[p] * 40 + bsg[p] * 8] = pbh[p];
            *(short8*)&Bl_s[bcol[p] * 40 + bsg[p] * 8] = pbl[p];
        }
        __syncthreads();
        short8 ah[4], bh[3], bl[3];
#pragma unroll
        for (int rf = 0; rf < 4; ++rf)
            ah[rf] = *(short8*)&A_s[(rf * 16 + ln) * 40 + quad * 8];
#pragma unroll
        for (int b = 0; b < 3; ++b) {
            int col = b * 64 + wave * 16 + ln;
            bh[b] = *(short8*)&Bh_s[col * 40 + quad * 8];
            bl[b] = *(short8*)&Bl_s[col * 40 + quad * 8];
        }
        int kn = k0 + 32;
        if (kn < KT) {
            int c0 = kn + asg * 8;
            pa = zero8;
            if (agm < NN) {
                pa = (c0 < F) ? *(const short8*)(xs_b + (size_t)agm * F + c0)
                              : *(const short8*)(agg_b + (size_t)agm * 8 * F + (c0 - F));
            }
#pragma unroll
            for (int p = 0; p < 3; ++p) {
                pbh[p] = *(const short8*)(Bh + (size_t)bcol[p] * KT + kn + bsg[p] * 8);
                pbl[p] = *(const short8*)(Bl + (size_t)bcol[p] * KT + kn + bsg[p] * 8);
            }
        }
#pragma unroll
        for (int rf = 0; rf < 4; ++rf)
#pragma unroll
            for (int b = 0; b < 3; ++b) {
                acc[rf][b] = __builtin_amdgcn_mfma_f32_16x16x32_bf16(ah[rf], bh[b], acc[rf][b], 0, 0, 0);
                acc[rf][b] = __builtin_amdgcn_mfma_f32_16x16x32_bf16(ah[rf], bl[b], acc[rf][b], 0, 0, 0);
            }
        __syncthreads();
    }

    int ocol = wave * 16 + ln;
    float bcolv = bias_zf[ocol];

#pragma unroll
    for (int rf = 0; rf < 4; ++rf) {
#pragma unroll
        for (int reg = 0; reg < 4; ++reg) {
            int r = rf * 16 + quad * 4 + reg;
            int gm = m0 + r;
            float2 s = make_float2(0.f, 0.f);
            if (gm < NN) s = sc[gm];
            float y = acc[rf][0][reg] + s.x * acc[rf][1][reg] + s.y * acc[rf][2][reg] + bcolv;
            y = fmaxf(y, 0.f);
            if (POOL) {
                hbuf[r * 68 + ocol] = (gm < NN) ? y : 0.f;
            } else if (gm < NN) {
                H[(size_t)gm * 64 + ocol] = y;
                H_b[(size_t)gm * 64 + ocol] = f2bf(y);
            }
        }
    }
    if (POOL) {
        __syncthreads();
        int col = tid & 63, grp = tid >> 6;
        float a = 0.f;
        int cur = -1;
        for (int i = 0; i < 16; ++i) {
            int r = grp * 16 + i;
            int gm = m0 + r;
            if (gm >= NN) break;
            int b = batch[gm];
            if (b != cur) {
                if (cur >= 0) atomicAdd(&pool[cur * 64 + col], a);
                cur = b; a = 0.f;
            }
            a += hbuf[r * 68 + col];
        }
        if (cur >= 0) atomicAdd(&pool[cur * 64 + col], a);
    }
}

__global__ __launch_bounds__(256) void head_kernel(const float* __restrict__ gpool, const float* __restrict__ hls,
                                                   const float* __restrict__ W1, const float* __restrict__ b1,
                                                   const float* __restrict__ W2, const float* __restrict__ b2,
                                                   const float* __restrict__ W3, const float* __restrict__ b3,
                                                   float* __restrict__ out) {
    __shared__ float gin[64][96];
    __shared__ float r1[64][64];
    __shared__ float r2[64][64];
    int tid = threadIdx.x;
    for (int idx = tid; idx < 64 * 96; idx += 256) {
        int g = idx / 96, j = idx % 96;
        gin[g][j] = (j < 64) ? gpool[g * 64 + j] : hls[g * 32 + (j - 64)];
    }
    __syncthreads();
    for (int idx = tid; idx < 64 * 64; idx += 256) {
        int g = idx / 64, j = idx % 64;
        float acc = b1[j];
        for (int k = 0; k < 96; ++k) acc = fmaf(gin[g][k], W1[k * 64 + j], acc);
        r1[g][j] = fmaxf(acc, 0.f);
    }
    __syncthreads();
    for (int idx = tid; idx < 64 * 64; idx += 256) {
        int g = idx / 64, j = idx % 64;
        float acc = b2[j];
        for (int k = 0; k < 64; ++k) acc = fmaf(r1[g][k], W2[k * 64 + j], acc);
        r2[g][j] = fmaxf(acc, 0.f);
    }
    __syncthreads();
    if (tid < 64) {
        float acc = b3[0];
        for (int k = 0; k < 64; ++k) acc = fmaf(r2[tid][k], W3[k], acc);
        out[tid] = acc;
    }
}

extern "C" void kernel_launch(void* const* d_in, const int* in_sizes, int n_in,
                              void* d_out, int out_size, void* d_ws, size_t ws_size,
                              hipStream_t stream) {
    (void)in_sizes; (void)n_in; (void)out_size; (void)ws_size;
    const float* x     = (const float*)d_in[0];
    const float* eattr = (const float*)d_in[1];
    const float* hls   = (const float*)d_in[2];
    const int*   eidx  = (const int*)d_in[3];
    const int*   batch = (const int*)d_in[4];
    const float* We[2]    = {(const float*)d_in[5],  (const float*)d_in[13]};
    const float* be[2]    = {(const float*)d_in[6],  (const float*)d_in[14]};
    const float* Wpre[2]  = {(const float*)d_in[7],  (const float*)d_in[15]};
    const float* bpre[2]  = {(const float*)d_in[8],  (const float*)d_in[16]};
    const float* Wpost[2] = {(const float*)d_in[9],  (const float*)d_in[17]};
    const float* bpost[2] = {(const float*)d_in[10], (const float*)d_in[18]};
    const float* Wlin[2]  = {(const float*)d_in[11], (const float*)d_in[19]};
    const float* blin[2]  = {(const float*)d_in[12], (const float*)d_in[20]};
    const float* W1 = (const float*)d_in[21]; const float* b1 = (const float*)d_in[22];
    const float* W2 = (const float*)d_in[23]; const float* b2 = (const float*)d_in[24];
    const float* W3 = (const float*)d_in[25]; const float* b3 = (const float*)d_in[26];
    float* out = (float*)d_out;

    char* ws = (char*)d_ws;
    size_t off = 0;
    auto carve = [&](size_t bytes) -> char* {
        char* p = ws + off;
        off = (off + bytes + 255) & ~(size_t)255;
        return p;
    };
    int*      cnt      = (int*)carve((size_t)NN * 4);
    float4*   csr      = (float4*)carve((size_t)NN * CAP * 16);
    float*    ABa      = (float*)carve((size_t)NN * 128 * 4);
    ushort_t* ABb      = (ushort_t*)carve((size_t)NN * 128 * 2);
    ushort_t* agg_b    = (ushort_t*)carve((size_t)NN * 512 * 2);
    float2*   sc       = (float2*)carve((size_t)NN * 8);
    ushort_t* xs_b     = (ushort_t*)carve((size_t)NN * 32 * 2);
    float*    h1       = (float*)carve((size_t)NN * 64 * 4);
    ushort_t* h1_b     = (ushort_t*)carve((size_t)NN * 64 * 2);
    float*    U0       = (float*)carve(256 * 4);
    float*    U1       = (float*)carve(256 * 4);
    float*    Wab0     = (float*)carve(16384 * 4);
    float*    Wab1     = (float*)carve(16384 * 4);
    float*    bias_ab0 = (float*)carve(256 * 4);
    float*    bias_ab1 = (float*)carve(256 * 4);
    ushort_t* Bh0      = (ushort_t*)carve((size_t)192 * 288 * 2);
    ushort_t* Bl0      = (ushort_t*)carve((size_t)192 * 288 * 2);
    ushort_t* Bh1      = (ushort_t*)carve((size_t)192 * 576 * 2);
    ushort_t* Bl1      = (ushort_t*)carve((size_t)192 * 576 * 2);
    float*    bias_zf0 = (float*)carve(64 * 4);
    float*    bias_zf1 = (float*)carve(64 * 4);
    float*    pool     = (float*)carve(64 * 64 * 4);

    const int MB128 = (NN + 127) / 128;  // 391
    const int MB64  = (NN + 63) / 64;    // 782
    const int SMEM_ZF = (64 * 40 + 192 * 40 + 192 * 40) * 2;  // 35840

    init_kernel<<<(NN * 32 + 255) / 256, 256, 0, stream>>>(cnt, pool, x, xs_b);
    build_csr<<<(EE + 255) / 256, 256, 0, stream>>>(eidx, eattr, cnt, csr);
    prep_all<<<26, 256, 0, stream>>>(We[0], be[0], Wpre[0], bpre[0], Wpost[0], Wlin[0], bpost[0], blin[0],
                                     We[1], be[1], Wpre[1], bpre[1], Wpost[1], Wlin[1], bpost[1], blin[1],
                                     U0, Wab0, bias_ab0, Bh0, Bl0, bias_zf0,
                                     U1, Wab1, bias_ab1, Bh1, Bl1, bias_zf1);

    // ---------------- layer 0 (F=32, TF=64, KT=288) ----------------
    gemm_bias<<<dim3(MB128, 2), 256, 0, stream>>>(x, Wab0, bias_ab0, ABa, ABb, NN, 32, 128, 64);
    aggregate<32><<<(NN + 3) / 4, 256, 0, stream>>>(ABa, ABb, cnt, csr, U0, agg_b, sc);
    gemm_zf<32, false><<<MB64, 256, SMEM_ZF, stream>>>(xs_b, agg_b, Bh0, Bl0, bias_zf0, sc,
                                                       h1, h1_b, batch, pool);

    // ---------------- layer 1 (F=64, TF=128, KT=576) ----------------
    gemm_bias<<<dim3(MB128, 4), 256, 0, stream>>>(h1, Wab1, bias_ab1, ABa, ABb, NN, 64, 256, 128);
    aggregate<64><<<(NN + 3) / 4, 256, 0, stream>>>(ABa, ABb, cnt, csr, U1, agg_b, sc);
    gemm_zf<64, true><<<MB64, 256, SMEM_ZF, stream>>>(h1_b, agg_b, Bh1, Bl1, bias_zf1, sc,
                                                      nullptr, nullptr, batch, pool);

    // ---------------- head ----------------
    head_kernel<<<1, 256, 0, stream>>>(pool, hls, W1, b1, W2, b2, W3, b3, out);
}

// Round 14
// 405.361 us; speedup vs baseline: 1.3376x; 1.0763x over previous
//
#include <hip/hip_runtime.h>
#include <math.h>
#include <float.h>

// Problem constants (HierNet_55705725829422)
#define NN 50000      // nodes
#define EE 800000     // edges
#define CAP 64        // max in-degree capacity (Poisson(16): P(>=64) ~ 1e-19)

typedef unsigned short ushort_t;
typedef short short8 __attribute__((ext_vector_type(8)));
typedef float floatx4 __attribute__((ext_vector_type(4)));
typedef float vfloat4 __attribute__((ext_vector_type(4)));

__device__ __constant__ float kAVG_LOG = 2.8332133440562162f; // log(17)

__device__ inline ushort_t f2bf(float v) {
    union { float f; unsigned u; } x; x.f = v;
    unsigned r = x.u + 0x7fffu + ((x.u >> 16) & 1u);
    return (ushort_t)(r >> 16);
}
__device__ inline float bf2f(ushort_t b) {
    union { unsigned u; float f; } x; x.u = ((unsigned)b) << 16; return x.f;
}
__device__ inline float bitsf(unsigned u) {
    union { unsigned u; float f; } x; x.u = u; return x.f;
}
__device__ inline void splitbf(float v, ushort_t& hi, ushort_t& lo) {
    hi = f2bf(v);
    lo = f2bf(v - bf2f(hi));
}

// merged init: zero cnt+pool, cast x -> bf16
__global__ __launch_bounds__(256) void init_kernel(int* cnt, float* pool, const float* __restrict__ x,
                                                   ushort_t* __restrict__ xb) {
    int i = blockIdx.x * 256 + threadIdx.x;
    if (i < NN * 32) xb[i] = f2bf(x[i]);
    if (i < NN) cnt[i] = 0;
    if (i < 64 * 64) pool[i] = 0.f;
}

// CSR build: CAP-padded buckets, packed 16B entries, 1 edge/thread, nt store.
__global__ __launch_bounds__(256) void build_csr(const int* __restrict__ ei, const float* __restrict__ ea,
                                                 int* __restrict__ cnt, float4* __restrict__ csr) {
    int e = blockIdx.x * 256 + threadIdx.x;
    if (e >= EE) return;
    int s = ei[e];
    int d = ei[EE + e];
    float2 v = *(const float2*)(ea + 2 * e);
    int p = atomicAdd(&cnt[d], 1);
    if (p < CAP) {
        vfloat4 w = {bitsf((unsigned)s), v.x, v.y, 0.f};
        __builtin_nontemporal_store(w, (vfloat4*)&csr[d * CAP + p]);
    }
}

// ---------------- fused weight prep: flat, 1 element/thread (TLP-hidden latency) ----------------
template <int F>
__device__ void prep_ab_dev(const float* __restrict__ We, const float* __restrict__ be,
                            const float* __restrict__ Wpre, const float* __restrict__ bpre,
                            float* __restrict__ U, float* __restrict__ Wab,
                            float* __restrict__ bias_ab) {
    const int TF = 2 * F;
    int tid = threadIdx.x;
    for (int idx = tid; idx < 2 * TF; idx += 256) {
        int c = idx / TF, f = idx % TF;
        int t = f / F, o = f % F;
        float s = 0.f;
        for (int g = 0; g < F; ++g)
            s += We[c * F + g] * Wpre[((size_t)t * 3 * F + 2 * F + g) * F + o];
        U[idx] = s;
    }
    for (int idx = tid; idx < F * 2 * TF; idx += 256) {
        int g = idx / (2 * TF), cc = idx % (2 * TF);
        int t, o, row;
        if (cc < TF) { t = cc / F; o = cc % F; row = g; }
        else { int c2 = cc - TF; t = c2 / F; o = c2 % F; row = F + g; }
        Wab[idx] = Wpre[((size_t)t * 3 * F + row) * F + o];
    }
    for (int cc = tid; cc < 2 * TF; cc += 256) {
        float v = 0.f;
        if (cc < TF) {
            int t = cc / F, o = cc % F;
            float s = 0.f;
            for (int g = 0; g < F; ++g)
                s += be[g] * Wpre[((size_t)t * 3 * F + 2 * F + g) * F + o];
            v = s + bpre[t * F + o];
        }
        bias_ab[cc] = v;
    }
}

template <int F>
__device__ void prep_zf_elem(int idx, const float* __restrict__ Wpost, const float* __restrict__ Wlin,
                             ushort_t* __restrict__ Bh, ushort_t* __restrict__ Bl) {
    const int KT = 9 * F;
    int jg = idx / KT, k = idx - jg * KT;
    int b = jg >> 6, j = jg & 63;
    float v = 0.f;
    if (k < F) {
        if (b == 0) {
#pragma unroll
            for (int t = 0; t < 2; ++t)
#pragma unroll
                for (int c = 0; c < 32; ++c)
                    v += Wpost[((size_t)t * 13 * F + k) * 32 + c] * Wlin[(t * 32 + c) * 64 + j];
        }
    } else {
        int r = k - F;
        int t = r / (4 * F), rr = r - t * 4 * F;
#pragma unroll
        for (int c = 0; c < 32; ++c)
            v += Wpost[((size_t)t * 13 * F + F + b * 4 * F + rr) * 32 + c] * Wlin[(t * 32 + c) * 64 + j];
    }
    ushort_t h_, l_;
    splitbf(v, h_, l_);
    Bh[(size_t)jg * KT + k] = h_;
    Bl[(size_t)jg * KT + k] = l_;
}

#define NZ0 216   // 192*288/256
#define NZ1 432   // 192*576/256

__global__ __launch_bounds__(256) void prep_all(
    const float* We0, const float* be0, const float* Wpre0, const float* bpre0,
    const float* Wpost0, const float* Wlin0, const float* bpost0, const float* blin0,
    const float* We1, const float* be1, const float* Wpre1, const float* bpre1,
    const float* Wpost1, const float* Wlin1, const float* bpost1, const float* blin1,
    float* U0, float* Wab0, float* bias_ab0, ushort_t* Bh0, ushort_t* Bl0, float* bias_zf0,
    float* U1, float* Wab1, float* bias_ab1, ushort_t* Bh1, ushort_t* Bl1, float* bias_zf1) {
    int b = blockIdx.x;
    int tid = threadIdx.x;
    if (b < NZ0) {
        prep_zf_elem<32>(b * 256 + tid, Wpost0, Wlin0, Bh0, Bl0);
    } else if (b < NZ0 + NZ1) {
        prep_zf_elem<64>((b - NZ0) * 256 + tid, Wpost1, Wlin1, Bh1, Bl1);
    } else if (b == NZ0 + NZ1) {
        prep_ab_dev<32>(We0, be0, Wpre0, bpre0, U0, Wab0, bias_ab0);
    } else if (b == NZ0 + NZ1 + 1) {
        prep_ab_dev<64>(We1, be1, Wpre1, bpre1, U1, Wab1, bias_ab1);
    } else {
        for (int j = tid; j < 64; j += 256) {
            float s0 = blin0[j], s1 = blin1[j];
#pragma unroll
            for (int t = 0; t < 2; ++t)
#pragma unroll
                for (int c = 0; c < 32; ++c) {
                    s0 += bpost0[t * 32 + c] * Wlin0[(t * 32 + c) * 64 + j];
                    s1 += bpost1[t * 32 + c] * Wlin1[(t * 32 + c) * 64 + j];
                }
            bias_zf0[j] = s0;
            bias_zf1[j] = s1;
        }
    }
}

// fp32 GEMM: [Ca | Cb] = A[MxK]@B[KxN] + bias. Columns < bstart -> fp32 Ca; >= bstart -> bf16 Cb.
__global__ __launch_bounds__(256) void gemm_bias(const float* __restrict__ A, const float* __restrict__ B,
                                                 const float* __restrict__ bias, float* __restrict__ Ca,
                                                 ushort_t* __restrict__ Cb, int M, int K, int Ncols, int bstart) {
    __shared__ float As[32][132];
    __shared__ float Bs[32][68];
    int m0 = blockIdx.x * 128, c0 = blockIdx.y * 64;
    int tid = threadIdx.x;
    int tx = tid & 15, ty = tid >> 4;
    int ms = tid >> 3, u = tid & 7;
    float acc[8][4] = {};
    for (int k0 = 0; k0 < K; k0 += 32) {
#pragma unroll
        for (int p = 0; p < 4; ++p) {
            int m = ms + 32 * p;
            int gm = m0 + m;
            float4 v = make_float4(0.f, 0.f, 0.f, 0.f);
            if (gm < M) v = *(const float4*)(A + (size_t)gm * K + k0 + u * 4);
            As[u * 4 + 0][m] = v.x; As[u * 4 + 1][m] = v.y;
            As[u * 4 + 2][m] = v.z; As[u * 4 + 3][m] = v.w;
        }
#pragma unroll
        for (int p = 0; p < 2; ++p) {
            int idx = tid + 256 * p;
            int kk = idx >> 4, q = idx & 15;
            *(float4*)&Bs[kk][q * 4] = *(const float4*)(B + (size_t)(k0 + kk) * Ncols + c0 + q * 4);
        }
        __syncthreads();
#pragma unroll 8
        for (int k = 0; k < 32; ++k) {
            float a0[8], b0[4];
            *(float4*)&a0[0] = *(const float4*)&As[k][ty * 8];
            *(float4*)&a0[4] = *(const float4*)&As[k][ty * 8 + 4];
            *(float4*)&b0[0] = *(const float4*)&Bs[k][tx * 4];
#pragma unroll
            for (int i = 0; i < 8; ++i)
#pragma unroll
                for (int j = 0; j < 4; ++j) acc[i][j] = fmaf(a0[i], b0[j], acc[i][j]);
        }
        __syncthreads();
    }
    float bj[4];
#pragma unroll
    for (int j = 0; j < 4; ++j) bj[j] = bias[c0 + tx * 4 + j];
    bool bside = (c0 >= bstart);
    int TFw = bstart;
#pragma unroll
    for (int i = 0; i < 8; ++i) {
        int gm = m0 + ty * 8 + i;
        if (gm >= M) continue;
        float v0 = acc[i][0] + bj[0], v1 = acc[i][1] + bj[1];
        float v2 = acc[i][2] + bj[2], v3 = acc[i][3] + bj[3];
        if (!bside) {
            *(float4*)(Ca + (size_t)gm * TFw + c0 + tx * 4) = make_float4(v0, v1, v2, v3);
        } else {
            ushort4 w;
            w.x = f2bf(v0); w.y = f2bf(v1); w.z = f2bf(v2); w.w = f2bf(v3);
            *(ushort4*)(Cb + (size_t)gm * TFw + (c0 - bstart) + tx * 4) = w;
        }
    }
}

// aggregate: ONE wave per node, lane-parallel entry load + shfl broadcast,
// guard-free 8-edge main chunks + guarded tail. bf16 gather, bf16 agg output.
template <int F>
__global__ __launch_bounds__(256) void aggregate(const float* __restrict__ ABa, const ushort_t* __restrict__ ABb,
                                                 const int* __restrict__ cnt, const float4* __restrict__ csr,
                                                 const float* __restrict__ U,
                                                 ushort_t* __restrict__ agg_b, float2* __restrict__ sc) {
    const int TF = 2 * F;
    const int FPL = TF / 64;  // 1 (F=32) or 2 (F=64)
    int lane = threadIdx.x & 63;
    int n = blockIdx.x * 4 + (threadIdx.x >> 6);
    if (n >= NN) return;
    int f0 = FPL * lane;

    float base[FPL], u0[FPL], u1[FPL], sum[FPL], sq[FPL], mn[FPL], mx[FPL];
#pragma unroll
    for (int r = 0; r < FPL; ++r) {
        base[r] = ABa[(size_t)n * TF + f0 + r];
        u0[r] = U[f0 + r];
        u1[r] = U[TF + f0 + r];
        sum[r] = 0.f; sq[r] = 0.f; mn[r] = FLT_MAX; mx[r] = -FLT_MAX;
    }
    int deg = cnt[n];
    int ec = deg < CAP ? deg : CAP;
    if (ec > 0) {
        int ebase = n * CAP;
        int myi = lane < ec ? lane : ec - 1;
        float4 ent = csr[ebase + myi];
        int msrc = __float_as_int(ent.x);
        float meax = ent.y, meay = ent.z;
        int e = 0;
        for (; e + 8 <= ec; e += 8) {
            int sb[8]; float ex[8], ey[8];
            unsigned wv[8];
#pragma unroll
            for (int i = 0; i < 8; ++i) {
                sb[i] = __shfl(msrc, e + i);
                ex[i] = __shfl(meax, e + i);
                ey[i] = __shfl(meay, e + i);
            }
#pragma unroll
            for (int i = 0; i < 8; ++i) {
                if constexpr (FPL == 2)
                    wv[i] = *(const unsigned*)(ABb + (size_t)sb[i] * TF + f0);
                else
                    wv[i] = ABb[(size_t)sb[i] * TF + f0];
            }
#pragma unroll
            for (int i = 0; i < 8; ++i) {
                float v[FPL];
                if constexpr (FPL == 2) {
                    v[0] = bitsf(wv[i] << 16);
                    v[1] = bitsf(wv[i] & 0xffff0000u);
                } else {
                    v[0] = bitsf(wv[i] << 16);
                }
#pragma unroll
                for (int r = 0; r < FPL; ++r) {
                    float q = fmaf(ex[i], u0[r], fmaf(ey[i], u1[r], v[r]));
                    sum[r] += q;
                    sq[r] = fmaf(q, q, sq[r]);
                    mn[r] = fminf(mn[r], q);
                    mx[r] = fmaxf(mx[r], q);
                }
            }
        }
        if (e < ec) {
            int sb[8]; float ex[8], ey[8];
            unsigned wv[8];
#pragma unroll
            for (int i = 0; i < 8; ++i) {
                sb[i] = __shfl(msrc, e + i);
                ex[i] = __shfl(meax, e + i);
                ey[i] = __shfl(meay, e + i);
            }
#pragma unroll
            for (int i = 0; i < 8; ++i) {
                if (e + i < ec) {
                    if constexpr (FPL == 2)
                        wv[i] = *(const unsigned*)(ABb + (size_t)sb[i] * TF + f0);
                    else
                        wv[i] = ABb[(size_t)sb[i] * TF + f0];
                }
            }
#pragma unroll
            for (int i = 0; i < 8; ++i) {
                if (e + i < ec) {
                    float v[FPL];
                    if constexpr (FPL == 2) {
                        v[0] = bitsf(wv[i] << 16);
                        v[1] = bitsf(wv[i] & 0xffff0000u);
                    } else {
                        v[0] = bitsf(wv[i] << 16);
                    }
#pragma unroll
                    for (int r = 0; r < FPL; ++r) {
                        float q = fmaf(ex[i], u0[r], fmaf(ey[i], u1[r], v[r]));
                        sum[r] += q;
                        sq[r] = fmaf(q, q, sq[r]);
                        mn[r] = fminf(mn[r], q);
                        mx[r] = fmaxf(mx[r], q);
                    }
                }
            }
        }
    }
    float d = (float)(deg > 1 ? deg : 1);
    float inv_d = 1.f / d;
    bool has = deg > 0;
#pragma unroll
    for (int r = 0; r < FPL; ++r) {
        float mean_q = sum[r] * inv_d;
        float var = sq[r] * inv_d - mean_q * mean_q;
        float stdv = sqrtf(fmaxf(var, 0.f) + 1e-5f);
        float mean = has ? base[r] + mean_q : 0.f;
        float vmn = has ? base[r] + mn[r] : 0.f;
        float vmx = has ? base[r] + mx[r] : 0.f;
        int f = f0 + r;
        int t = f / F, o = f - t * F;
        size_t rowb = (size_t)n * (4 * TF) + (size_t)t * (4 * F);
        agg_b[rowb + o] = f2bf(mean);
        agg_b[rowb + F + o] = f2bf(vmn);
        agg_b[rowb + 2 * F + o] = f2bf(vmx);
        agg_b[rowb + 3 * F + o] = f2bf(stdv);
    }
    if (lane == 0) {
        float logd = logf(d + 1.f);
        sc[n] = make_float2(logd / kAVG_LOG, kAVG_LOG / logd);
    }
}

// MFMA merged Z+final GEMM. A bf16 (single), B split hi/lo: Y = Ah@Bh + Ah@Bl.
// Block 64 rows x 192 cols; wave w owns col-frags {w, w+4, w+8} x 4 row-frags.
// Register-prefetch pipeline: k0+1 global loads issued before k0's MFMA block.
template <int F, bool POOL>
__global__ __launch_bounds__(256) void gemm_zf(
    const ushort_t* __restrict__ xs_b, const ushort_t* __restrict__ agg_b,
    const ushort_t* __restrict__ Bh, const ushort_t* __restrict__ Bl,
    const float* __restrict__ bias_zf, const float2* __restrict__ sc,
    float* __restrict__ H, ushort_t* __restrict__ H_b,
    const int* __restrict__ batch, float* __restrict__ pool) {
    const int KT = 9 * F;
    extern __shared__ char smem[];
    ushort_t* A_s  = (ushort_t*)smem;        // [64][40]
    ushort_t* Bh_s = A_s + 64 * 40;          // [192][40]
    ushort_t* Bl_s = Bh_s + 192 * 40;        // [192][40]
    float* hbuf = (float*)smem;              // POOL alias [64][68]

    int m0 = blockIdx.x * 64;
    int tid = threadIdx.x;
    int lane = tid & 63;
    int wave = tid >> 6;
    int ln = lane & 15, quad = lane >> 4;

    floatx4 acc[4][3];
#pragma unroll
    for (int i = 0; i < 4; ++i)
#pragma unroll
        for (int j = 0; j < 3; ++j) acc[i][j] = (floatx4)(0.f);

    int arow = tid >> 2, asg = tid & 3;
    int agm = m0 + arow;
    int bcol[3], bsg[3];
#pragma unroll
    for (int p = 0; p < 3; ++p) {
        int idx = tid + 256 * p;
        bcol[p] = idx >> 2;
        bsg[p] = idx & 3;
    }

    const short8 zero8 = {0, 0, 0, 0, 0, 0, 0, 0};
    short8 pa, pbh[3], pbl[3];
    {
        int c0 = asg * 8;
        pa = zero8;
        if (agm < NN) pa = *(const short8*)(xs_b + (size_t)agm * F + c0);
#pragma unroll
        for (int p = 0; p < 3; ++p) {
            pbh[p] = *(const short8*)(Bh + (size_t)bcol[p] * KT + bsg[p] * 8);
            pbl[p] = *(const short8*)(Bl + (size_t)bcol[p] * KT + bsg[p] * 8);
        }
    }

    for (int k0 = 0; k0 < KT; k0 += 32) {
        *(short8*)&A_s[arow * 40 + asg * 8] = pa;
#pragma unroll
        for (int p = 0; p < 3; ++p) {
            *(short8*)&Bh_s[bcol[p] * 40 + bsg[p] * 8] = pbh[p];
            *(short8*)&Bl_s[bcol[p] * 40 + bsg[p] * 8] = pbl[p];
        }
        __syncthreads();
        short8 ah[4], bh[3], bl[3];
#pragma unroll
        for (int rf = 0; rf < 4; ++rf)
            ah[rf] = *(short8*)&A_s[(rf * 16 + ln) * 40 + quad * 8];
#pragma unroll
        for (int b = 0; b < 3; ++b) {
            int col = b * 64 + wave * 16 + ln;
            bh[b] = *(short8*)&Bh_s[col * 40 + quad * 8];
            bl[b] = *(short8*)&Bl_s[col * 40 + quad * 8];
        }
        int kn = k0 + 32;
        if (kn < KT) {
            int c0 = kn + asg * 8;
            pa = zero8;
            if (agm < NN) {
                pa = (c0 < F) ? *(const short8*)(xs_b + (size_t)agm * F + c0)
                              : *(const short8*)(agg_b + (size_t)agm * 8 * F + (c0 - F));
            }
#pragma unroll
            for (int p = 0; p < 3; ++p) {
                pbh[p] = *(const short8*)(Bh + (size_t)bcol[p] * KT + kn + bsg[p] * 8);
                pbl[p] = *(const short8*)(Bl + (size_t)bcol[p] * KT + kn + bsg[p] * 8);
            }
        }
#pragma unroll
        for (int rf = 0; rf < 4; ++rf)
#pragma unroll
            for (int b = 0; b < 3; ++b) {
                acc[rf][b] = __builtin_amdgcn_mfma_f32_16x16x32_bf16(ah[rf], bh[b], acc[rf][b], 0, 0, 0);
                acc[rf][b] = __builtin_amdgcn_mfma_f32_16x16x32_bf16(ah[rf], bl[b], acc[rf][b], 0, 0, 0);
            }
        __syncthreads();
    }

    int ocol = wave * 16 + ln;
    float bcolv = bias_zf[ocol];

#pragma unroll
    for (int rf = 0; rf < 4; ++rf) {
#pragma unroll
        for (int reg = 0; reg < 4; ++reg) {
            int r = rf * 16 + quad * 4 + reg;
            int gm = m0 + r;
            float2 s = make_float2(0.f, 0.f);
            if (gm < NN) s = sc[gm];
            float y = acc[rf][0][reg] + s.x * acc[rf][1][reg] + s.y * acc[rf][2][reg] + bcolv;
            y = fmaxf(y, 0.f);
            if (POOL) {
                hbuf[r * 68 + ocol] = (gm < NN) ? y : 0.f;
            } else if (gm < NN) {
                H[(size_t)gm * 64 + ocol] = y;
                H_b[(size_t)gm * 64 + ocol] = f2bf(y);
            }
        }
    }
    if (POOL) {
        __syncthreads();
        int col = tid & 63, grp = tid >> 6;
        float a = 0.f;
        int cur = -1;
        for (int i = 0; i < 16; ++i) {
            int r = grp * 16 + i;
            int gm = m0 + r;
            if (gm >= NN) break;
            int b = batch[gm];
            if (b != cur) {
                if (cur >= 0) atomicAdd(&pool[cur * 64 + col], a);
                cur = b; a = 0.f;
            }
            a += hbuf[r * 68 + col];
        }
        if (cur >= 0) atomicAdd(&pool[cur * 64 + col], a);
    }
}

__global__ __launch_bounds__(256) void head_kernel(const float* __restrict__ gpool, const float* __restrict__ hls,
                                                   const float* __restrict__ W1, const float* __restrict__ b1,
                                                   const float* __restrict__ W2, const float* __restrict__ b2,
                                                   const float* __restrict__ W3, const float* __restrict__ b3,
                                                   float* __restrict__ out) {
    __shared__ float gin[64][96];
    __shared__ float r1[64][64];
    __shared__ float r2[64][64];
    int tid = threadIdx.x;
    for (int idx = tid; idx < 64 * 96; idx += 256) {
        int g = idx / 96, j = idx % 96;
        gin[g][j] = (j < 64) ? gpool[g * 64 + j] : hls[g * 32 + (j - 64)];
    }
    __syncthreads();
    for (int idx = tid; idx < 64 * 64; idx += 256) {
        int g = idx / 64, j = idx % 64;
        float acc = b1[j];
        for (int k = 0; k < 96; ++k) acc = fmaf(gin[g][k], W1[k * 64 + j], acc);
        r1[g][j] = fmaxf(acc, 0.f);
    }
    __syncthreads();
    for (int idx = tid; idx < 64 * 64; idx += 256) {
        int g = idx / 64, j = idx % 64;
        float acc = b2[j];
        for (int k = 0; k < 64; ++k) acc = fmaf(r1[g][k], W2[k * 64 + j], acc);
        r2[g][j] = fmaxf(acc, 0.f);
    }
    __syncthreads();
    if (tid < 64) {
        float acc = b3[0];
        for (int k = 0; k < 64; ++k) acc = fmaf(r2[tid][k], W3[k], acc);
        out[tid] = acc;
    }
}

extern "C" void kernel_launch(void* const* d_in, const int* in_sizes, int n_in,
                              void* d_out, int out_size, void* d_ws, size_t ws_size,
                              hipStream_t stream) {
    (void)in_sizes; (void)n_in; (void)out_size; (void)ws_size;
    const float* x     = (const float*)d_in[0];
    const float* eattr = (const float*)d_in[1];
    const float* hls   = (const float*)d_in[2];
    const int*   eidx  = (const int*)d_in[3];
    const int*   batch = (const int*)d_in[4];
    const float* We[2]    = {(const float*)d_in[5],  (const float*)d_in[13]};
    const float* be[2]    = {(const float*)d_in[6],  (const float*)d_in[14]};
    const float* Wpre[2]  = {(const float*)d_in[7],  (const float*)d_in[15]};
    const float* bpre[2]  = {(const float*)d_in[8],  (const float*)d_in[16]};
    const float* Wpost[2] = {(const float*)d_in[9],  (const float*)d_in[17]};
    const float* bpost[2] = {(const float*)d_in[10], (const float*)d_in[18]};
    const float* Wlin[2]  = {(const float*)d_in[11], (const float*)d_in[19]};
    const float* blin[2]  = {(const float*)d_in[12], (const float*)d_in[20]};
    const float* W1 = (const float*)d_in[21]; const float* b1 = (const float*)d_in[22];
    const float* W2 = (const float*)d_in[23]; const float* b2 = (const float*)d_in[24];
    const float* W3 = (const float*)d_in[25]; const float* b3 = (const float*)d_in[26];
    float* out = (float*)d_out;

    char* ws = (char*)d_ws;
    size_t off = 0;
    auto carve = [&](size_t bytes) -> char* {
        char* p = ws + off;
        off = (off + bytes + 255) & ~(size_t)255;
        return p;
    };
    int*      cnt      = (int*)carve((size_t)NN * 4);
    float4*   csr      = (float4*)carve((size_t)NN * CAP * 16);
    float*    ABa      = (float*)carve((size_t)NN * 128 * 4);
    ushort_t* ABb      = (ushort_t*)carve((size_t)NN * 128 * 2);
    ushort_t* agg_b    = (ushort_t*)carve((size_t)NN * 512 * 2);
    float2*   sc       = (float2*)carve((size_t)NN * 8);
    ushort_t* xs_b     = (ushort_t*)carve((size_t)NN * 32 * 2);
    float*    h1       = (float*)carve((size_t)NN * 64 * 4);
    ushort_t* h1_b     = (ushort_t*)carve((size_t)NN * 64 * 2);
    float*    U0       = (float*)carve(256 * 4);
    float*    U1       = (float*)carve(256 * 4);
    float*    Wab0     = (float*)carve(16384 * 4);
    float*    Wab1     = (float*)carve(16384 * 4);
    float*    bias_ab0 = (float*)carve(256 * 4);
    float*    bias_ab1 = (float*)carve(256 * 4);
    ushort_t* Bh0      = (ushort_t*)carve((size_t)192 * 288 * 2);
    ushort_t* Bl0      = (ushort_t*)carve((size_t)192 * 288 * 2);
    ushort_t* Bh1      = (ushort_t*)carve((size_t)192 * 576 * 2);
    ushort_t* Bl1      = (ushort_t*)carve((size_t)192 * 576 * 2);
    float*    bias_zf0 = (float*)carve(64 * 4);
    float*    bias_zf1 = (float*)carve(64 * 4);
    float*    pool     = (float*)carve(64 * 64 * 4);

    const int MB128 = (NN + 127) / 128;  // 391
    const int MB64  = (NN + 63) / 64;    // 782
    const int SMEM_ZF = (64 * 40 + 192 * 40 + 192 * 40) * 2;  // 35840

    init_kernel<<<(NN * 32 + 255) / 256, 256, 0, stream>>>(cnt, pool, x, xs_b);
    build_csr<<<(EE + 255) / 256, 256, 0, stream>>>(eidx, eattr, cnt, csr);
    prep_all<<<NZ0 + NZ1 + 3, 256, 0, stream>>>(
        We[0], be[0], Wpre[0], bpre[0], Wpost[0], Wlin[0], bpost[0], blin[0],
        We[1], be[1], Wpre[1], bpre[1], Wpost[1], Wlin[1], bpost[1], blin[1],
        U0, Wab0, bias_ab0, Bh0, Bl0, bias_zf0,
        U1, Wab1, bias_ab1, Bh1, Bl1, bias_zf1);

    // ---------------- layer 0 (F=32, TF=64, KT=288) ----------------
    gemm_bias<<<dim3(MB128, 2), 256, 0, stream>>>(x, Wab0, bias_ab0, ABa, ABb, NN, 32, 128, 64);
    aggregate<32><<<(NN + 3) / 4, 256, 0, stream>>>(ABa, ABb, cnt, csr, U0, agg_b, sc);
    gemm_zf<32, false><<<MB64, 256, SMEM_ZF, stream>>>(xs_b, agg_b, Bh0, Bl0, bias_zf0, sc,
                                                       h1, h1_b, batch, pool);

    // ---------------- layer 1 (F=64, TF=128, KT=576) ----------------
    gemm_bias<<<dim3(MB128, 4), 256, 0, stream>>>(h1, Wab1, bias_ab1, ABa, ABb, NN, 64, 256, 128);
    aggregate<64><<<(NN + 3) / 4, 256, 0, stream>>>(ABa, ABb, cnt, csr, U1, agg_b, sc);
    gemm_zf<64, true><<<MB64, 256, SMEM_ZF, stream>>>(h1_b, agg_b, Bh1, Bl1, bias_zf1, sc,
                                                      nullptr, nullptr, batch, pool);

    // ---------------- head ----------------
    head_kernel<<<1, 256, 0, stream>>>(pool, hls, W1, b1, W2, b2, W3, b3, out);
}

// Round 15
// 396.677 us; speedup vs baseline: 1.3669x; 1.0219x over previous
//
#include <hip/hip_runtime.h>
#include <math.h>
#include <float.h>

// Problem constants (HierNet_55705725829422)
#define NN 50000      // nodes
#define EE 800000     // edges
#define CAP 64        // max in-degree capacity (Poisson(16): P(>=64) ~ 1e-19)

typedef unsigned short ushort_t;
typedef short short8 __attribute__((ext_vector_type(8)));
typedef float floatx4 __attribute__((ext_vector_type(4)));

__device__ __constant__ float kAVG_LOG = 2.8332133440562162f; // log(17)

__device__ inline ushort_t f2bf(float v) {
    union { float f; unsigned u; } x; x.f = v;
    unsigned r = x.u + 0x7fffu + ((x.u >> 16) & 1u);
    return (ushort_t)(r >> 16);
}
__device__ inline float bf2f(ushort_t b) {
    union { unsigned u; float f; } x; x.u = ((unsigned)b) << 16; return x.f;
}
__device__ inline float bitsf(unsigned u) {
    union { unsigned u; float f; } x; x.u = u; return x.f;
}
__device__ inline void splitbf(float v, ushort_t& hi, ushort_t& lo) {
    hi = f2bf(v);
    lo = f2bf(v - bf2f(hi));
}

// merged init: zero cnt+pool, cast x -> bf16
__global__ __launch_bounds__(256) void init_kernel(int* cnt, float* pool, const float* __restrict__ x,
                                                   ushort_t* __restrict__ xb) {
    int i = blockIdx.x * 256 + threadIdx.x;
    if (i < NN * 32) xb[i] = f2bf(x[i]);
    if (i < NN) cnt[i] = 0;
    if (i < 64 * 64) pool[i] = 0.f;
}

// CSR build: CAP-padded buckets, packed 8B entries {src, bf16(ea.y)<<16 | bf16(ea.x)},
// 1 edge/thread, plain stores (L2/L3 line combining).
__global__ __launch_bounds__(256) void build_csr(const int* __restrict__ ei, const float* __restrict__ ea,
                                                 int* __restrict__ cnt, uint2* __restrict__ csr) {
    int e = blockIdx.x * 256 + threadIdx.x;
    if (e >= EE) return;
    int s = ei[e];
    int d = ei[EE + e];
    float2 v = *(const float2*)(ea + 2 * e);
    int p = atomicAdd(&cnt[d], 1);
    if (p < CAP) {
        uint2 w;
        w.x = (unsigned)s;
        w.y = ((unsigned)f2bf(v.y) << 16) | (unsigned)f2bf(v.x);
        csr[d * CAP + p] = w;
    }
}

// ---------------- fused weight prep: flat, 1 element/thread (TLP-hidden latency) ----------------
template <int F>
__device__ void prep_ab_dev(const float* __restrict__ We, const float* __restrict__ be,
                            const float* __restrict__ Wpre, const float* __restrict__ bpre,
                            float* __restrict__ U, float* __restrict__ Wab,
                            float* __restrict__ bias_ab) {
    const int TF = 2 * F;
    int tid = threadIdx.x;
    for (int idx = tid; idx < 2 * TF; idx += 256) {
        int c = idx / TF, f = idx % TF;
        int t = f / F, o = f % F;
        float s = 0.f;
        for (int g = 0; g < F; ++g)
            s += We[c * F + g] * Wpre[((size_t)t * 3 * F + 2 * F + g) * F + o];
        U[idx] = s;
    }
    for (int idx = tid; idx < F * 2 * TF; idx += 256) {
        int g = idx / (2 * TF), cc = idx % (2 * TF);
        int t, o, row;
        if (cc < TF) { t = cc / F; o = cc % F; row = g; }
        else { int c2 = cc - TF; t = c2 / F; o = c2 % F; row = F + g; }
        Wab[idx] = Wpre[((size_t)t * 3 * F + row) * F + o];
    }
    for (int cc = tid; cc < 2 * TF; cc += 256) {
        float v = 0.f;
        if (cc < TF) {
            int t = cc / F, o = cc % F;
            float s = 0.f;
            for (int g = 0; g < F; ++g)
                s += be[g] * Wpre[((size_t)t * 3 * F + 2 * F + g) * F + o];
            v = s + bpre[t * F + o];
        }
        bias_ab[cc] = v;
    }
}

template <int F>
__device__ void prep_zf_elem(int idx, const float* __restrict__ Wpost, const float* __restrict__ Wlin,
                             ushort_t* __restrict__ Bh, ushort_t* __restrict__ Bl) {
    const int KT = 9 * F;
    int jg = idx / KT, k = idx - jg * KT;
    int b = jg >> 6, j = jg & 63;
    float v = 0.f;
    if (k < F) {
        if (b == 0) {
#pragma unroll
            for (int t = 0; t < 2; ++t)
#pragma unroll
                for (int c = 0; c < 32; ++c)
                    v += Wpost[((size_t)t * 13 * F + k) * 32 + c] * Wlin[(t * 32 + c) * 64 + j];
        }
    } else {
        int r = k - F;
        int t = r / (4 * F), rr = r - t * 4 * F;
#pragma unroll
        for (int c = 0; c < 32; ++c)
            v += Wpost[((size_t)t * 13 * F + F + b * 4 * F + rr) * 32 + c] * Wlin[(t * 32 + c) * 64 + j];
    }
    ushort_t h_, l_;
    splitbf(v, h_, l_);
    Bh[(size_t)jg * KT + k] = h_;
    Bl[(size_t)jg * KT + k] = l_;
}

#define NZ0 216   // 192*288/256
#define NZ1 432   // 192*576/256

__global__ __launch_bounds__(256) void prep_all(
    const float* We0, const float* be0, const float* Wpre0, const float* bpre0,
    const float* Wpost0, const float* Wlin0, const float* bpost0, const float* blin0,
    const float* We1, const float* be1, const float* Wpre1, const float* bpre1,
    const float* Wpost1, const float* Wlin1, const float* bpost1, const float* blin1,
    float* U0, float* Wab0, float* bias_ab0, ushort_t* Bh0, ushort_t* Bl0, float* bias_zf0,
    float* U1, float* Wab1, float* bias_ab1, ushort_t* Bh1, ushort_t* Bl1, float* bias_zf1) {
    int b = blockIdx.x;
    int tid = threadIdx.x;
    if (b < NZ0) {
        prep_zf_elem<32>(b * 256 + tid, Wpost0, Wlin0, Bh0, Bl0);
    } else if (b < NZ0 + NZ1) {
        prep_zf_elem<64>((b - NZ0) * 256 + tid, Wpost1, Wlin1, Bh1, Bl1);
    } else if (b == NZ0 + NZ1) {
        prep_ab_dev<32>(We0, be0, Wpre0, bpre0, U0, Wab0, bias_ab0);
    } else if (b == NZ0 + NZ1 + 1) {
        prep_ab_dev<64>(We1, be1, Wpre1, bpre1, U1, Wab1, bias_ab1);
    } else {
        for (int j = tid; j < 64; j += 256) {
            float s0 = blin0[j], s1 = blin1[j];
#pragma unroll
            for (int t = 0; t < 2; ++t)
#pragma unroll
                for (int c = 0; c < 32; ++c) {
                    s0 += bpost0[t * 32 + c] * Wlin0[(t * 32 + c) * 64 + j];
                    s1 += bpost1[t * 32 + c] * Wlin1[(t * 32 + c) * 64 + j];
                }
            bias_zf0[j] = s0;
            bias_zf1[j] = s1;
        }
    }
}

// fp32 GEMM: [Ca | Cb] = A[MxK]@B[KxN] + bias. Columns < bstart -> fp32 Ca; >= bstart -> bf16 Cb.
__global__ __launch_bounds__(256) void gemm_bias(const float* __restrict__ A, const float* __restrict__ B,
                                                 const float* __restrict__ bias, float* __restrict__ Ca,
                                                 ushort_t* __restrict__ Cb, int M, int K, int Ncols, int bstart) {
    __shared__ float As[32][132];
    __shared__ float Bs[32][68];
    int m0 = blockIdx.x * 128, c0 = blockIdx.y * 64;
    int tid = threadIdx.x;
    int tx = tid & 15, ty = tid >> 4;
    int ms = tid >> 3, u = tid & 7;
    float acc[8][4] = {};
    for (int k0 = 0; k0 < K; k0 += 32) {
#pragma unroll
        for (int p = 0; p < 4; ++p) {
            int m = ms + 32 * p;
            int gm = m0 + m;
            float4 v = make_float4(0.f, 0.f, 0.f, 0.f);
            if (gm < M) v = *(const float4*)(A + (size_t)gm * K + k0 + u * 4);
            As[u * 4 + 0][m] = v.x; As[u * 4 + 1][m] = v.y;
            As[u * 4 + 2][m] = v.z; As[u * 4 + 3][m] = v.w;
        }
#pragma unroll
        for (int p = 0; p < 2; ++p) {
            int idx = tid + 256 * p;
            int kk = idx >> 4, q = idx & 15;
            *(float4*)&Bs[kk][q * 4] = *(const float4*)(B + (size_t)(k0 + kk) * Ncols + c0 + q * 4);
        }
        __syncthreads();
#pragma unroll 8
        for (int k = 0; k < 32; ++k) {
            float a0[8], b0[4];
            *(float4*)&a0[0] = *(const float4*)&As[k][ty * 8];
            *(float4*)&a0[4] = *(const float4*)&As[k][ty * 8 + 4];
            *(float4*)&b0[0] = *(const float4*)&Bs[k][tx * 4];
#pragma unroll
            for (int i = 0; i < 8; ++i)
#pragma unroll
                for (int j = 0; j < 4; ++j) acc[i][j] = fmaf(a0[i], b0[j], acc[i][j]);
        }
        __syncthreads();
    }
    float bj[4];
#pragma unroll
    for (int j = 0; j < 4; ++j) bj[j] = bias[c0 + tx * 4 + j];
    bool bside = (c0 >= bstart);
    int TFw = bstart;
#pragma unroll
    for (int i = 0; i < 8; ++i) {
        int gm = m0 + ty * 8 + i;
        if (gm >= M) continue;
        float v0 = acc[i][0] + bj[0], v1 = acc[i][1] + bj[1];
        float v2 = acc[i][2] + bj[2], v3 = acc[i][3] + bj[3];
        if (!bside) {
            *(float4*)(Ca + (size_t)gm * TFw + c0 + tx * 4) = make_float4(v0, v1, v2, v3);
        } else {
            ushort4 w;
            w.x = f2bf(v0); w.y = f2bf(v1); w.z = f2bf(v2); w.w = f2bf(v3);
            *(ushort4*)(Cb + (size_t)gm * TFw + (c0 - bstart) + tx * 4) = w;
        }
    }
}

// aggregate: ONE wave per node, 8B CSR entries (src + bf16 ea pair), shfl broadcast,
// guard-free 8-edge main chunks + guarded tail. bf16 gather, bf16 agg output.
template <int F>
__global__ __launch_bounds__(256) void aggregate(const float* __restrict__ ABa, const ushort_t* __restrict__ ABb,
                                                 const int* __restrict__ cnt, const uint2* __restrict__ csr,
                                                 const float* __restrict__ U,
                                                 ushort_t* __restrict__ agg_b, float2* __restrict__ sc) {
    const int TF = 2 * F;
    const int FPL = TF / 64;  // 1 (F=32) or 2 (F=64)
    int lane = threadIdx.x & 63;
    int n = blockIdx.x * 4 + (threadIdx.x >> 6);
    if (n >= NN) return;
    int f0 = FPL * lane;

    float base[FPL], u0[FPL], u1[FPL], sum[FPL], sq[FPL], mn[FPL], mx[FPL];
#pragma unroll
    for (int r = 0; r < FPL; ++r) {
        base[r] = ABa[(size_t)n * TF + f0 + r];
        u0[r] = U[f0 + r];
        u1[r] = U[TF + f0 + r];
        sum[r] = 0.f; sq[r] = 0.f; mn[r] = FLT_MAX; mx[r] = -FLT_MAX;
    }
    int deg = cnt[n];
    int ec = deg < CAP ? deg : CAP;
    if (ec > 0) {
        int ebase = n * CAP;
        int myi = lane < ec ? lane : ec - 1;
        uint2 ent = csr[ebase + myi];
        int msrc = (int)ent.x;
        unsigned mea = ent.y;
        int e = 0;
        for (; e + 8 <= ec; e += 8) {
            int sb[8]; unsigned ep[8];
            unsigned wv[8];
#pragma unroll
            for (int i = 0; i < 8; ++i) {
                sb[i] = __shfl(msrc, e + i);
                ep[i] = (unsigned)__shfl((int)mea, e + i);
            }
#pragma unroll
            for (int i = 0; i < 8; ++i) {
                if constexpr (FPL == 2)
                    wv[i] = *(const unsigned*)(ABb + (size_t)sb[i] * TF + f0);
                else
                    wv[i] = ABb[(size_t)sb[i] * TF + f0];
            }
#pragma unroll
            for (int i = 0; i < 8; ++i) {
                float ex = bitsf(ep[i] << 16);
                float ey = bitsf(ep[i] & 0xffff0000u);
                float v[FPL];
                if constexpr (FPL == 2) {
                    v[0] = bitsf(wv[i] << 16);
                    v[1] = bitsf(wv[i] & 0xffff0000u);
                } else {
                    v[0] = bitsf(wv[i] << 16);
                }
#pragma unroll
                for (int r = 0; r < FPL; ++r) {
                    float q = fmaf(ex, u0[r], fmaf(ey, u1[r], v[r]));
                    sum[r] += q;
                    sq[r] = fmaf(q, q, sq[r]);
                    mn[r] = fminf(mn[r], q);
                    mx[r] = fmaxf(mx[r], q);
                }
            }
        }
        if (e < ec) {
            int sb[8]; unsigned ep[8];
            unsigned wv[8];
#pragma unroll
            for (int i = 0; i < 8; ++i) {
                sb[i] = __shfl(msrc, e + i);
                ep[i] = (unsigned)__shfl((int)mea, e + i);
            }
#pragma unroll
            for (int i = 0; i < 8; ++i) {
                if (e + i < ec) {
                    if constexpr (FPL == 2)
                        wv[i] = *(const unsigned*)(ABb + (size_t)sb[i] * TF + f0);
                    else
                        wv[i] = ABb[(size_t)sb[i] * TF + f0];
                }
            }
#pragma unroll
            for (int i = 0; i < 8; ++i) {
                if (e + i < ec) {
                    float ex = bitsf(ep[i] << 16);
                    float ey = bitsf(ep[i] & 0xffff0000u);
                    float v[FPL];
                    if constexpr (FPL == 2) {
                        v[0] = bitsf(wv[i] << 16);
                        v[1] = bitsf(wv[i] & 0xffff0000u);
                    } else {
                        v[0] = bitsf(wv[i] << 16);
                    }
#pragma unroll
                    for (int r = 0; r < FPL; ++r) {
                        float q = fmaf(ex, u0[r], fmaf(ey, u1[r], v[r]));
                        sum[r] += q;
                        sq[r] = fmaf(q, q, sq[r]);
                        mn[r] = fminf(mn[r], q);
                        mx[r] = fmaxf(mx[r], q);
                    }
                }
            }
        }
    }
    float d = (float)(deg > 1 ? deg : 1);
    float inv_d = 1.f / d;
    bool has = deg > 0;
#pragma unroll
    for (int r = 0; r < FPL; ++r) {
        float mean_q = sum[r] * inv_d;
        float var = sq[r] * inv_d - mean_q * mean_q;
        float stdv = sqrtf(fmaxf(var, 0.f) + 1e-5f);
        float mean = has ? base[r] + mean_q : 0.f;
        float vmn = has ? base[r] + mn[r] : 0.f;
        float vmx = has ? base[r] + mx[r] : 0.f;
        int f = f0 + r;
        int t = f / F, o = f - t * F;
        size_t rowb = (size_t)n * (4 * TF) + (size_t)t * (4 * F);
        agg_b[rowb + o] = f2bf(mean);
        agg_b[rowb + F + o] = f2bf(vmn);
        agg_b[rowb + 2 * F + o] = f2bf(vmx);
        agg_b[rowb + 3 * F + o] = f2bf(stdv);
    }
    if (lane == 0) {
        float logd = logf(d + 1.f);
        sc[n] = make_float2(logd / kAVG_LOG, kAVG_LOG / logd);
    }
}

// MFMA merged Z+final GEMM. A bf16 via LDS; B (hi/lo, <=442 KB, L2-resident) read
// DIRECTLY from global into registers each k0 — no B LDS round-trip.
// Block 64 rows x 192 cols; wave w owns col-frags {w, w+4, w+8} x 4 row-frags.
template <int F, bool POOL>
__global__ __launch_bounds__(256) void gemm_zf(
    const ushort_t* __restrict__ xs_b, const ushort_t* __restrict__ agg_b,
    const ushort_t* __restrict__ Bh, const ushort_t* __restrict__ Bl,
    const float* __restrict__ bias_zf, const float2* __restrict__ sc,
    float* __restrict__ H, ushort_t* __restrict__ H_b,
    const int* __restrict__ batch, float* __restrict__ pool) {
    const int KT = 9 * F;
    extern __shared__ char smem[];
    ushort_t* A_s = (ushort_t*)smem;   // [64][40] = 5.1 KB
    float* hbuf = (float*)smem;        // POOL alias [64][68] = 17.4 KB

    int m0 = blockIdx.x * 64;
    int tid = threadIdx.x;
    int lane = tid & 63;
    int wave = tid >> 6;
    int ln = lane & 15, quad = lane >> 4;

    floatx4 acc[4][3];
#pragma unroll
    for (int i = 0; i < 4; ++i)
#pragma unroll
        for (int j = 0; j < 3; ++j) acc[i][j] = (floatx4)(0.f);

    int arow = tid >> 2, asg = tid & 3;
    int agm = m0 + arow;

    // per-wave B fragment base pointers (col-major [192][KT])
    const ushort_t* Bhp[3];
    const ushort_t* Blp[3];
#pragma unroll
    for (int b = 0; b < 3; ++b) {
        int col = b * 64 + wave * 16 + ln;
        Bhp[b] = Bh + (size_t)col * KT + quad * 8;
        Blp[b] = Bl + (size_t)col * KT + quad * 8;
    }

    const short8 zero8 = {0, 0, 0, 0, 0, 0, 0, 0};
    short8 pa;
    {
        int c0 = asg * 8;  // always < F at k0=0
        pa = zero8;
        if (agm < NN) pa = *(const short8*)(xs_b + (size_t)agm * F + c0);
    }

    for (int k0 = 0; k0 < KT; k0 += 32) {
        *(short8*)&A_s[arow * 40 + asg * 8] = pa;
        __syncthreads();
        // issue B global loads early (L2-hit; overlap with LDS reads + A prefetch)
        short8 bh[3], bl[3];
#pragma unroll
        for (int b = 0; b < 3; ++b) {
            bh[b] = *(const short8*)(Bhp[b] + k0);
            bl[b] = *(const short8*)(Blp[b] + k0);
        }
        short8 ah[4];
#pragma unroll
        for (int rf = 0; rf < 4; ++rf)
            ah[rf] = *(short8*)&A_s[(rf * 16 + ln) * 40 + quad * 8];
        int kn = k0 + 32;
        if (kn < KT) {
            int c0 = kn + asg * 8;
            pa = zero8;
            if (agm < NN) {
                pa = (c0 < F) ? *(const short8*)(xs_b + (size_t)agm * F + c0)
                              : *(const short8*)(agg_b + (size_t)agm * 8 * F + (c0 - F));
            }
        }
#pragma unroll
        for (int rf = 0; rf < 4; ++rf)
#pragma unroll
            for (int b = 0; b < 3; ++b) {
                acc[rf][b] = __builtin_amdgcn_mfma_f32_16x16x32_bf16(ah[rf], bh[b], acc[rf][b], 0, 0, 0);
                acc[rf][b] = __builtin_amdgcn_mfma_f32_16x16x32_bf16(ah[rf], bl[b], acc[rf][b], 0, 0, 0);
            }
        __syncthreads();
    }

    int ocol = wave * 16 + ln;
    float bcolv = bias_zf[ocol];

#pragma unroll
    for (int rf = 0; rf < 4; ++rf) {
#pragma unroll
        for (int reg = 0; reg < 4; ++reg) {
            int r = rf * 16 + quad * 4 + reg;
            int gm = m0 + r;
            float2 s = make_float2(0.f, 0.f);
            if (gm < NN) s = sc[gm];
            float y = acc[rf][0][reg] + s.x * acc[rf][1][reg] + s.y * acc[rf][2][reg] + bcolv;
            y = fmaxf(y, 0.f);
            if (POOL) {
                hbuf[r * 68 + ocol] = (gm < NN) ? y : 0.f;
            } else if (gm < NN) {
                H[(size_t)gm * 64 + ocol] = y;
                H_b[(size_t)gm * 64 + ocol] = f2bf(y);
            }
        }
    }
    if (POOL) {
        __syncthreads();
        int col = tid & 63, grp = tid >> 6;
        float a = 0.f;
        int cur = -1;
        for (int i = 0; i < 16; ++i) {
            int r = grp * 16 + i;
            int gm = m0 + r;
            if (gm >= NN) break;
            int b = batch[gm];
            if (b != cur) {
                if (cur >= 0) atomicAdd(&pool[cur * 64 + col], a);
                cur = b; a = 0.f;
            }
            a += hbuf[r * 68 + col];
        }
        if (cur >= 0) atomicAdd(&pool[cur * 64 + col], a);
    }
}

__global__ __launch_bounds__(256) void head_kernel(const float* __restrict__ gpool, const float* __restrict__ hls,
                                                   const float* __restrict__ W1, const float* __restrict__ b1,
                                                   const float* __restrict__ W2, const float* __restrict__ b2,
                                                   const float* __restrict__ W3, const float* __restrict__ b3,
                                                   float* __restrict__ out) {
    __shared__ float gin[64][96];
    __shared__ float r1[64][64];
    __shared__ float r2[64][64];
    int tid = threadIdx.x;
    for (int idx = tid; idx < 64 * 96; idx += 256) {
        int g = idx / 96, j = idx % 96;
        gin[g][j] = (j < 64) ? gpool[g * 64 + j] : hls[g * 32 + (j - 64)];
    }
    __syncthreads();
    for (int idx = tid; idx < 64 * 64; idx += 256) {
        int g = idx / 64, j = idx % 64;
        float acc = b1[j];
        for (int k = 0; k < 96; ++k) acc = fmaf(gin[g][k], W1[k * 64 + j], acc);
        r1[g][j] = fmaxf(acc, 0.f);
    }
    __syncthreads();
    for (int idx = tid; idx < 64 * 64; idx += 256) {
        int g = idx / 64, j = idx % 64;
        float acc = b2[j];
        for (int k = 0; k < 64; ++k) acc = fmaf(r1[g][k], W2[k * 64 + j], acc);
        r2[g][j] = fmaxf(acc, 0.f);
    }
    __syncthreads();
    if (tid < 64) {
        float acc = b3[0];
        for (int k = 0; k < 64; ++k) acc = fmaf(r2[tid][k], W3[k], acc);
        out[tid] = acc;
    }
}

extern "C" void kernel_launch(void* const* d_in, const int* in_sizes, int n_in,
                              void* d_out, int out_size, void* d_ws, size_t ws_size,
                              hipStream_t stream) {
    (void)in_sizes; (void)n_in; (void)out_size; (void)ws_size;
    const float* x     = (const float*)d_in[0];
    const float* eattr = (const float*)d_in[1];
    const float* hls   = (const float*)d_in[2];
    const int*   eidx  = (const int*)d_in[3];
    const int*   batch = (const int*)d_in[4];
    const float* We[2]    = {(const float*)d_in[5],  (const float*)d_in[13]};
    const float* be[2]    = {(const float*)d_in[6],  (const float*)d_in[14]};
    const float* Wpre[2]  = {(const float*)d_in[7],  (const float*)d_in[15]};
    const float* bpre[2]  = {(const float*)d_in[8],  (const float*)d_in[16]};
    const float* Wpost[2] = {(const float*)d_in[9],  (const float*)d_in[17]};
    const float* bpost[2] = {(const float*)d_in[10], (const float*)d_in[18]};
    const float* Wlin[2]  = {(const float*)d_in[11], (const float*)d_in[19]};
    const float* blin[2]  = {(const float*)d_in[12], (const float*)d_in[20]};
    const float* W1 = (const float*)d_in[21]; const float* b1 = (const float*)d_in[22];
    const float* W2 = (const float*)d_in[23]; const float* b2 = (const float*)d_in[24];
    const float* W3 = (const float*)d_in[25]; const float* b3 = (const float*)d_in[26];
    float* out = (float*)d_out;

    char* ws = (char*)d_ws;
    size_t off = 0;
    auto carve = [&](size_t bytes) -> char* {
        char* p = ws + off;
        off = (off + bytes + 255) & ~(size_t)255;
        return p;
    };
    int*      cnt      = (int*)carve((size_t)NN * 4);
    uint2*    csr      = (uint2*)carve((size_t)NN * CAP * 8);
    float*    ABa      = (float*)carve((size_t)NN * 128 * 4);
    ushort_t* ABb      = (ushort_t*)carve((size_t)NN * 128 * 2);
    ushort_t* agg_b    = (ushort_t*)carve((size_t)NN * 512 * 2);
    float2*   sc       = (float2*)carve((size_t)NN * 8);
    ushort_t* xs_b     = (ushort_t*)carve((size_t)NN * 32 * 2);
    float*    h1       = (float*)carve((size_t)NN * 64 * 4);
    ushort_t* h1_b     = (ushort_t*)carve((size_t)NN * 64 * 2);
    float*    U0       = (float*)carve(256 * 4);
    float*    U1       = (float*)carve(256 * 4);
    float*    Wab0     = (float*)carve(16384 * 4);
    float*    Wab1     = (float*)carve(16384 * 4);
    float*    bias_ab0 = (float*)carve(256 * 4);
    float*    bias_ab1 = (float*)carve(256 * 4);
    ushort_t* Bh0      = (ushort_t*)carve((size_t)192 * 288 * 2);
    ushort_t* Bl0      = (ushort_t*)carve((size_t)192 * 288 * 2);
    ushort_t* Bh1      = (ushort_t*)carve((size_t)192 * 576 * 2);
    ushort_t* Bl1      = (ushort_t*)carve((size_t)192 * 576 * 2);
    float*    bias_zf0 = (float*)carve(64 * 4);
    float*    bias_zf1 = (float*)carve(64 * 4);
    float*    pool     = (float*)carve(64 * 64 * 4);

    const int MB128 = (NN + 127) / 128;  // 391
    const int MB64  = (NN + 63) / 64;    // 782
    const int SMEM_MAIN = 64 * 40 * 2;   // 5120 (A-only)
    const int SMEM_POOL = 64 * 68 * 4;   // 17408 (hbuf alias, > A_s)

    init_kernel<<<(NN * 32 + 255) / 256, 256, 0, stream>>>(cnt, pool, x, xs_b);
    build_csr<<<(EE + 255) / 256, 256, 0, stream>>>(eidx, eattr, cnt, csr);
    prep_all<<<NZ0 + NZ1 + 3, 256, 0, stream>>>(
        We[0], be[0], Wpre[0], bpre[0], Wpost[0], Wlin[0], bpost[0], blin[0],
        We[1], be[1], Wpre[1], bpre[1], Wpost[1], Wlin[1], bpost[1], blin[1],
        U0, Wab0, bias_ab0, Bh0, Bl0, bias_zf0,
        U1, Wab1, bias_ab1, Bh1, Bl1, bias_zf1);

    // ---------------- layer 0 (F=32, TF=64, KT=288) ----------------
    gemm_bias<<<dim3(MB128, 2), 256, 0, stream>>>(x, Wab0, bias_ab0, ABa, ABb, NN, 32, 128, 64);
    aggregate<32><<<(NN + 3) / 4, 256, 0, stream>>>(ABa, ABb, cnt, csr, U0, agg_b, sc);
    gemm_zf<32, false><<<MB64, 256, SMEM_MAIN, stream>>>(xs_b, agg_b, Bh0, Bl0, bias_zf0, sc,
                                                         h1, h1_b, batch, pool);

    // ---------------- layer 1 (F=64, TF=128, KT=576) ----------------
    gemm_bias<<<dim3(MB128, 4), 256, 0, stream>>>(h1, Wab1, bias_ab1, ABa, ABb, NN, 64, 256, 128);
    aggregate<64><<<(NN + 3) / 4, 256, 0, stream>>>(ABa, ABb, cnt, csr, U1, agg_b, sc);
    gemm_zf<64, true><<<MB64, 256, SMEM_POOL, stream>>>(h1_b, agg_b, Bh1, Bl1, bias_zf1, sc,
                                                        nullptr, nullptr, batch, pool);

    // ---------------- head ----------------
    head_kernel<<<1, 256, 0, stream>>>(pool, hls, W1, b1, W2, b2, W3, b3, out);
}